// Round 1
// baseline (4098.237 us; speedup 1.0000x reference)
//
#include <hip/hip_runtime.h>
#include <math.h>

#define NN 50000
#define EE 1600000
#define IND 300
#define NL 3

__device__ __forceinline__ float sigf(float x) { return 1.0f / (1.0f + __expf(-x)); }

// ============================ CSR build ============================
__global__ void count_kernel(const int* __restrict__ dst, int* __restrict__ cnt) {
  int e = blockIdx.x * 256 + threadIdx.x;
  if (e < EE) atomicAdd(&cnt[dst[e]], 1);
}

// single-block hierarchical exclusive scan of cnt[0..NN) -> rs, rs[NN]=total
__global__ void scan_kernel(const int* __restrict__ cnt, int* __restrict__ rs) {
  __shared__ int wsum[16], wpre[16];
  __shared__ int carryS, totS;
  const int t = threadIdx.x;
  const int l = t & 63, wid = t >> 6;
  if (t == 0) carryS = 0;
  __syncthreads();
  for (int base = 0; base < NN; base += 1024) {
    const int carry = carryS;
    const int i = base + t;
    int v = (i < NN) ? cnt[i] : 0;
    int x = v;
    #pragma unroll
    for (int off = 1; off < 64; off <<= 1) {
      int y = __shfl_up(x, off);
      if (l >= off) x += y;
    }
    if (l == 63) wsum[wid] = x;
    __syncthreads();
    if (t < 16) {
      int s = wsum[t];
      int xx = s;
      #pragma unroll
      for (int off = 1; off < 16; off <<= 1) {
        int y = __shfl_up(xx, off);
        if (t >= off) xx += y;
      }
      wpre[t] = xx - s;
      if (t == 15) totS = xx;
    }
    __syncthreads();
    if (i < NN) rs[i] = carry + wpre[wid] + (x - v);
    __syncthreads();
    if (t == 0) carryS = carry + totS;
    __syncthreads();
  }
  if (t == 0) rs[NN] = carryS;
}

__global__ void fill_kernel(const int* __restrict__ dst, const int* __restrict__ rs,
                            int* __restrict__ ncnt, int* __restrict__ csr) {
  int e = blockIdx.x * 256 + threadIdx.x;
  if (e < EE) {
    int d = dst[e];
    int p = atomicAdd(&ncnt[d], 1);
    csr[rs[d] + p] = e;
  }
}

// ============================ head-fused weight precompute ============================
// W_all[i][hd*64+j] = sum_m Wv[hd][i][m] * Wd[m][j]
__global__ void wall_kernel(const float* __restrict__ Wv, const float* __restrict__ Wd,
                            float* __restrict__ Wall) {
  int i = blockIdx.x;   // 0..255
  int c = threadIdx.x;  // 0..255
  int hd = c >> 6, j = c & 63;
  const float* wv = &Wv[hd * (256 * 64) + i * 64];
  float s = 0.f;
  #pragma unroll
  for (int m = 0; m < 64; ++m) s = fmaf(wv[m], Wd[m * 64 + j], s);
  Wall[i * 256 + c] = s;
}

__global__ void ball_kernel(const float* __restrict__ bv, const float* __restrict__ Wd,
                            const float* __restrict__ bd, float* __restrict__ ball) {
  int c = threadIdx.x;
  int hd = c >> 6, j = c & 63;
  float s = bd[j];
  #pragma unroll
  for (int m = 0; m < 64; ++m) s = fmaf(bv[hd * 64 + m], Wd[m * 64 + j], s);
  ball[c] = s;
}

// ============================ input projection (role-selected) ============================
// h[n] = relu(X[n] @ Wsel(role) + bsel); pm = h
__global__ __launch_bounds__(256) void proj_kernel(
    const float* __restrict__ X, const int* __restrict__ role,
    const float* __restrict__ Wq, const float* __restrict__ bq,
    const float* __restrict__ We, const float* __restrict__ be,
    const float* __restrict__ Wc, const float* __restrict__ bc,
    float* __restrict__ h, float* __restrict__ pm) {
  __shared__ __align__(16) float As[16][68];
  __shared__ __align__(16) float Bs[3][16][68];
  const int t = threadIdx.x;
  const int c0 = blockIdx.x * 64;
  const int m0 = blockIdx.y * 64;
  const int tc = t & 15, tr = t >> 4;
  const int mm = t >> 2, kq = (t & 3) * 4;
  const int bkk = t >> 4, bcq = (t & 15) * 4;
  float acc[4][4] = {};
  int rws[4];
  #pragma unroll
  for (int i = 0; i < 4; ++i) {
    int r = m0 + tr * 4 + i;
    rws[i] = (r < NN) ? role[r] : 0;
  }
  const float* Ws[3] = {Wq, We, Wc};
  for (int k0 = 0; k0 < IND; k0 += 16) {
    {  // A tile (transposed into LDS)
      int r = m0 + mm;
      float4 a4 = make_float4(0.f, 0.f, 0.f, 0.f);
      if (r < NN) {
        if (k0 + 16 <= IND) {
          a4 = *(const float4*)&X[(size_t)r * IND + k0 + kq];
        } else {
          float tmp[4];
          #pragma unroll
          for (int i = 0; i < 4; ++i) {
            int k = k0 + kq + i;
            tmp[i] = (k < IND) ? X[(size_t)r * IND + k] : 0.f;
          }
          a4 = make_float4(tmp[0], tmp[1], tmp[2], tmp[3]);
        }
      }
      As[kq + 0][mm] = a4.x; As[kq + 1][mm] = a4.y;
      As[kq + 2][mm] = a4.z; As[kq + 3][mm] = a4.w;
    }
    {  // B tiles x3
      int k = k0 + bkk;
      #pragma unroll
      for (int w = 0; w < 3; ++w) {
        float4 b4 = make_float4(0.f, 0.f, 0.f, 0.f);
        if (k < IND) b4 = *(const float4*)&Ws[w][(size_t)k * 256 + c0 + bcq];
        *(float4*)&Bs[w][bkk][bcq] = b4;
      }
    }
    __syncthreads();
    #pragma unroll
    for (int kk = 0; kk < 16; ++kk) {
      float4 a = *(const float4*)&As[kk][tr * 4];
      float4 b0 = *(const float4*)&Bs[0][kk][tc * 4];
      float4 b1 = *(const float4*)&Bs[1][kk][tc * 4];
      float4 b2 = *(const float4*)&Bs[2][kk][tc * 4];
      const float av[4] = {a.x, a.y, a.z, a.w};
      #pragma unroll
      for (int i = 0; i < 4; ++i) {
        float4 b = (rws[i] == 0) ? b0 : (rws[i] == 1) ? b1 : b2;
        acc[i][0] = fmaf(av[i], b.x, acc[i][0]);
        acc[i][1] = fmaf(av[i], b.y, acc[i][1]);
        acc[i][2] = fmaf(av[i], b.z, acc[i][2]);
        acc[i][3] = fmaf(av[i], b.w, acc[i][3]);
      }
    }
    __syncthreads();
  }
  #pragma unroll
  for (int i = 0; i < 4; ++i) {
    int r = m0 + tr * 4 + i;
    if (r < NN) {
      const float* bb = (rws[i] == 0) ? bq : (rws[i] == 1) ? be : bc;
      int c = c0 + tc * 4;
      float4 o;
      o.x = fmaxf(acc[i][0] + bb[c + 0], 0.f);
      o.y = fmaxf(acc[i][1] + bb[c + 1], 0.f);
      o.z = fmaxf(acc[i][2] + bb[c + 2], 0.f);
      o.w = fmaxf(acc[i][3] + bb[c + 3], 0.f);
      *(float4*)&h[(size_t)r * 256 + c] = o;
      *(float4*)&pm[(size_t)r * 256 + c] = o;
    }
  }
}

// ============================ V = h @ Wall + ball ============================
__global__ __launch_bounds__(256) void vgemm_kernel(
    const float* __restrict__ A, const float* __restrict__ B,
    const float* __restrict__ bias, float* __restrict__ C) {
  __shared__ __align__(16) float As[16][68];
  __shared__ __align__(16) float Bs[16][68];
  const int t = threadIdx.x;
  const int c0 = blockIdx.x * 64;
  const int m0 = blockIdx.y * 64;
  const int tc = t & 15, tr = t >> 4;
  const int mm = t >> 2, kq = (t & 3) * 4;
  const int bkk = t >> 4, bcq = (t & 15) * 4;
  float acc[4][4] = {};
  for (int k0 = 0; k0 < 256; k0 += 16) {
    int r = m0 + mm;
    float4 a4 = make_float4(0.f, 0.f, 0.f, 0.f);
    if (r < NN) a4 = *(const float4*)&A[(size_t)r * 256 + k0 + kq];
    As[kq + 0][mm] = a4.x; As[kq + 1][mm] = a4.y;
    As[kq + 2][mm] = a4.z; As[kq + 3][mm] = a4.w;
    float4 b4 = *(const float4*)&B[(size_t)(k0 + bkk) * 256 + c0 + bcq];
    *(float4*)&Bs[bkk][bcq] = b4;
    __syncthreads();
    #pragma unroll
    for (int kk = 0; kk < 16; ++kk) {
      float4 a = *(const float4*)&As[kk][tr * 4];
      float4 b = *(const float4*)&Bs[kk][tc * 4];
      const float av[4] = {a.x, a.y, a.z, a.w};
      const float bv[4] = {b.x, b.y, b.z, b.w};
      #pragma unroll
      for (int i = 0; i < 4; ++i)
        #pragma unroll
        for (int j = 0; j < 4; ++j)
          acc[i][j] = fmaf(av[i], bv[j], acc[i][j]);
    }
    __syncthreads();
  }
  #pragma unroll
  for (int i = 0; i < 4; ++i) {
    int r = m0 + tr * 4 + i;
    if (r < NN) {
      int c = c0 + tc * 4;
      float4 o;
      o.x = acc[i][0] + bias[c + 0];
      o.y = acc[i][1] + bias[c + 1];
      o.z = acc[i][2] + bias[c + 2];
      o.w = acc[i][3] + bias[c + 3];
      *(float4*)&C[(size_t)r * 256 + c] = o;
    }
  }
}

// ============================ aggregation: comb[n] = sum_e w*V[src] ============================
__global__ __launch_bounds__(256) void agg_kernel(
    const int* __restrict__ csr, const int* __restrict__ rs,
    const int* __restrict__ esrc, const float* __restrict__ ew,
    const float* __restrict__ V, float* __restrict__ comb) {
  int n = blockIdx.x * 4 + (threadIdx.x >> 6);
  int l = threadIdx.x & 63;
  if (n >= NN) return;
  int s = rs[n], e = rs[n + 1];
  float4 acc = make_float4(0.f, 0.f, 0.f, 0.f);
  for (int j = s; j < e; ++j) {
    int eid = csr[j];
    int src = esrc[eid];
    float w = ew[eid];
    float4 v = *(const float4*)&V[(size_t)src * 256 + l * 4];
    acc.x = fmaf(w, v.x, acc.x);
    acc.y = fmaf(w, v.y, acc.y);
    acc.z = fmaf(w, v.z, acc.z);
    acc.w = fmaf(w, v.w, acc.w);
  }
  *(float4*)&comb[(size_t)n * 256 + l * 4] = acc;
}

// ============================ GRU pass1: R,Z = sigmoid(comb@Wih_rz^T + pm@Whh_rz^T + b) ============================
__global__ __launch_bounds__(256) void gru_rz_kernel(
    const float* __restrict__ comb, const float* __restrict__ pm,
    const float* __restrict__ Wih, const float* __restrict__ Whh,
    const float* __restrict__ bih, const float* __restrict__ bhh,
    float* __restrict__ R, float* __restrict__ Zb) {
  __shared__ __align__(16) float As[16][68];
  __shared__ __align__(16) float Bs[16][68];
  const int t = threadIdx.x;
  const int j0 = blockIdx.x * 64;  // 0..511
  const int m0 = blockIdx.y * 64;
  const int tc = t & 15, tr = t >> 4;
  const int mm = t >> 2, kq = (t & 3) * 4;
  const int jj = t >> 2, kq2 = (t & 3) * 4;
  float acc[4][4] = {};
  for (int half = 0; half < 2; ++half) {
    const float* __restrict__ Asrc = half ? pm : comb;
    const float* __restrict__ Wsrc = half ? Whh : Wih;
    for (int k0 = 0; k0 < 256; k0 += 16) {
      int r = m0 + mm;
      float4 a4 = make_float4(0.f, 0.f, 0.f, 0.f);
      if (r < NN) a4 = *(const float4*)&Asrc[(size_t)r * 256 + k0 + kq];
      As[kq + 0][mm] = a4.x; As[kq + 1][mm] = a4.y;
      As[kq + 2][mm] = a4.z; As[kq + 3][mm] = a4.w;
      // transposed weight tile: Bs[kk][jj] = W[(j0+jj)*256 + k0+kk]
      float4 b4 = *(const float4*)&Wsrc[(size_t)(j0 + jj) * 256 + k0 + kq2];
      Bs[kq2 + 0][jj] = b4.x; Bs[kq2 + 1][jj] = b4.y;
      Bs[kq2 + 2][jj] = b4.z; Bs[kq2 + 3][jj] = b4.w;
      __syncthreads();
      #pragma unroll
      for (int kk = 0; kk < 16; ++kk) {
        float4 a = *(const float4*)&As[kk][tr * 4];
        float4 b = *(const float4*)&Bs[kk][tc * 4];
        const float av[4] = {a.x, a.y, a.z, a.w};
        const float bv[4] = {b.x, b.y, b.z, b.w};
        #pragma unroll
        for (int i = 0; i < 4; ++i)
          #pragma unroll
          for (int j = 0; j < 4; ++j)
            acc[i][j] = fmaf(av[i], bv[j], acc[i][j]);
      }
      __syncthreads();
    }
  }
  #pragma unroll
  for (int i = 0; i < 4; ++i) {
    int r = m0 + tr * 4 + i;
    if (r < NN) {
      #pragma unroll
      for (int jx = 0; jx < 4; ++jx) {
        int j = j0 + tc * 4 + jx;
        float g = sigf(acc[i][jx] + bih[j] + bhh[j]);
        if (j < 256) R[(size_t)r * 256 + j] = g;
        else         Zb[(size_t)r * 256 + (j - 256)] = g;
      }
    }
  }
}

// ============================ GRU pass2: n-gate + state update (pm in place) ============================
__global__ __launch_bounds__(256) void gru_n_kernel(
    const float* __restrict__ comb, float* __restrict__ pm,
    const float* __restrict__ Wih, const float* __restrict__ Whh,
    const float* __restrict__ bih, const float* __restrict__ bhh,
    const float* __restrict__ R, const float* __restrict__ Zb) {
  __shared__ __align__(16) float As[16][20];
  __shared__ __align__(16) float Bs[16][264];
  const int t = threadIdx.x;
  const int l = t & 63, w = t >> 6;
  const int m0 = blockIdx.x * 16;
  const int amm = t >> 4, akk = t & 15;
  float acc_i[4][4] = {};
  float acc_h[4][4] = {};
  // half 0: i_n partial (A=comb, W=Wih rows 512..767)
  for (int k0 = 0; k0 < 256; k0 += 16) {
    As[akk][amm] = comb[(size_t)(m0 + amm) * 256 + k0 + akk];
    const float* wr = &Wih[(size_t)(512 + t) * 256 + k0];
    #pragma unroll
    for (int q = 0; q < 4; ++q) {
      float4 b4 = *(const float4*)&wr[q * 4];
      Bs[q * 4 + 0][t] = b4.x; Bs[q * 4 + 1][t] = b4.y;
      Bs[q * 4 + 2][t] = b4.z; Bs[q * 4 + 3][t] = b4.w;
    }
    __syncthreads();
    #pragma unroll
    for (int kk = 0; kk < 16; ++kk) {
      float4 a = *(const float4*)&As[kk][w * 4];
      float4 b = *(const float4*)&Bs[kk][l * 4];
      const float av[4] = {a.x, a.y, a.z, a.w};
      const float bv[4] = {b.x, b.y, b.z, b.w};
      #pragma unroll
      for (int i = 0; i < 4; ++i)
        #pragma unroll
        for (int j = 0; j < 4; ++j)
          acc_i[i][j] = fmaf(av[i], bv[j], acc_i[i][j]);
    }
    __syncthreads();
  }
  // half 1: h_n partial (A=pm, W=Whh rows 512..767)
  for (int k0 = 0; k0 < 256; k0 += 16) {
    As[akk][amm] = pm[(size_t)(m0 + amm) * 256 + k0 + akk];
    const float* wr = &Whh[(size_t)(512 + t) * 256 + k0];
    #pragma unroll
    for (int q = 0; q < 4; ++q) {
      float4 b4 = *(const float4*)&wr[q * 4];
      Bs[q * 4 + 0][t] = b4.x; Bs[q * 4 + 1][t] = b4.y;
      Bs[q * 4 + 2][t] = b4.z; Bs[q * 4 + 3][t] = b4.w;
    }
    __syncthreads();
    #pragma unroll
    for (int kk = 0; kk < 16; ++kk) {
      float4 a = *(const float4*)&As[kk][w * 4];
      float4 b = *(const float4*)&Bs[kk][l * 4];
      const float av[4] = {a.x, a.y, a.z, a.w};
      const float bv[4] = {b.x, b.y, b.z, b.w};
      #pragma unroll
      for (int i = 0; i < 4; ++i)
        #pragma unroll
        for (int j = 0; j < 4; ++j)
          acc_h[i][j] = fmaf(av[i], bv[j], acc_h[i][j]);
    }
    __syncthreads();
  }
  #pragma unroll
  for (int i = 0; i < 4; ++i) {
    const int r = m0 + w * 4 + i;
    #pragma unroll
    for (int j = 0; j < 4; ++j) {
      int c = l * 4 + j;
      float i_n = acc_i[i][j] + bih[512 + c];
      float h_n = acc_h[i][j] + bhh[512 + c];
      float rg = R[(size_t)r * 256 + c];
      float z = Zb[(size_t)r * 256 + c];
      float po = pm[(size_t)r * 256 + c];
      float nn = tanhf(i_n + rg * h_n);
      pm[(size_t)r * 256 + c] = (1.f - z) * nn + z * po;
    }
  }
}

// ============================ h = LN(prev_h + comb@Wo + bo) (in place on h) ============================
__global__ __launch_bounds__(256) void wo_ln_kernel(
    const float* __restrict__ comb, const float* __restrict__ Wo,
    const float* __restrict__ bo, float* __restrict__ h,
    const float* __restrict__ lnw, const float* __restrict__ lnb) {
  __shared__ __align__(16) float As[16][20];
  __shared__ __align__(16) float Bs[16][264];
  const int t = threadIdx.x;
  const int l = t & 63, w = t >> 6;
  const int m0 = blockIdx.x * 16;
  const int amm = t >> 4, akk = t & 15;
  const int bkk = t >> 4, bcq = (t & 15) * 16;
  float acc[4][4] = {};
  for (int k0 = 0; k0 < 256; k0 += 16) {
    As[akk][amm] = comb[(size_t)(m0 + amm) * 256 + k0 + akk];
    const float* wr = &Wo[(size_t)(k0 + bkk) * 256 + bcq];
    #pragma unroll
    for (int q = 0; q < 4; ++q)
      *(float4*)&Bs[bkk][bcq + q * 4] = *(const float4*)&wr[q * 4];
    __syncthreads();
    #pragma unroll
    for (int kk = 0; kk < 16; ++kk) {
      float4 a = *(const float4*)&As[kk][w * 4];
      float4 b = *(const float4*)&Bs[kk][l * 4];
      const float av[4] = {a.x, a.y, a.z, a.w};
      const float bv[4] = {b.x, b.y, b.z, b.w};
      #pragma unroll
      for (int i = 0; i < 4; ++i)
        #pragma unroll
        for (int j = 0; j < 4; ++j)
          acc[i][j] = fmaf(av[i], bv[j], acc[i][j]);
    }
    __syncthreads();
  }
  #pragma unroll
  for (int i = 0; i < 4; ++i) {
    const int r = m0 + w * 4 + i;
    float vals[4];
    float s = 0.f;
    #pragma unroll
    for (int j = 0; j < 4; ++j) {
      int c = l * 4 + j;
      float v = acc[i][j] + bo[c] + h[(size_t)r * 256 + c];
      vals[j] = v;
      s += v;
    }
    #pragma unroll
    for (int off = 1; off < 64; off <<= 1) s += __shfl_xor(s, off);
    float mu = s * (1.0f / 256.0f);
    float vsum = 0.f;
    #pragma unroll
    for (int j = 0; j < 4; ++j) {
      float d = vals[j] - mu;
      vsum += d * d;
    }
    #pragma unroll
    for (int off = 1; off < 64; off <<= 1) vsum += __shfl_xor(vsum, off);
    float inv = rsqrtf(vsum * (1.0f / 256.0f) + 1e-5f);
    int c = l * 4;
    float4 o;
    o.x = (vals[0] - mu) * inv * lnw[c + 0] + lnb[c + 0];
    o.y = (vals[1] - mu) * inv * lnw[c + 1] + lnb[c + 1];
    o.z = (vals[2] - mu) * inv * lnw[c + 2] + lnb[c + 2];
    o.w = (vals[3] - mu) * inv * lnw[c + 3] + lnb[c + 3];
    *(float4*)&h[(size_t)r * 256 + c] = o;
  }
}

// ============================ out = h + pm ============================
__global__ void add_kernel(const float* __restrict__ a, const float* __restrict__ b,
                           float* __restrict__ o) {
  int i = blockIdx.x * 256 + threadIdx.x;
  if (i < NN * 256 / 4) {
    float4 x = *(const float4*)&a[(size_t)i * 4];
    float4 y = *(const float4*)&b[(size_t)i * 4];
    float4 r;
    r.x = x.x + y.x; r.y = x.y + y.y; r.z = x.z + y.z; r.w = x.w + y.w;
    *(float4*)&o[(size_t)i * 4] = r;
  }
}

extern "C" void kernel_launch(void* const* d_in, const int* in_sizes, int n_in,
                              void* d_out, int out_size, void* d_ws, size_t ws_size,
                              hipStream_t stream) {
  const float* node_feats = (const float*)d_in[0];
  const int* role = (const int*)d_in[1];
  const int* esrc = (const int*)d_in[2];
  const int* edst = (const int*)d_in[3];
  const float* ew = (const float*)d_in[4];
  const float* Wq = (const float*)d_in[5];
  const float* bq = (const float*)d_in[6];
  const float* We = (const float*)d_in[7];
  const float* be = (const float*)d_in[8];
  const float* Wc = (const float*)d_in[9];
  const float* bc = (const float*)d_in[10];
  const float* Wv = (const float*)d_in[11];
  const float* bv = (const float*)d_in[12];
  const float* Wd = (const float*)d_in[13];
  const float* bd = (const float*)d_in[14];
  const float* Wo = (const float*)d_in[15];
  const float* bo = (const float*)d_in[16];
  const float* Wih = (const float*)d_in[17];
  const float* Whh = (const float*)d_in[18];
  const float* bih = (const float*)d_in[19];
  const float* bhh = (const float*)d_in[20];
  const float* lnw = (const float*)d_in[21];
  const float* lnb = (const float*)d_in[22];
  float* out = (float*)d_out;

  char* ws = (char*)d_ws;
  size_t o = 0;
  auto take = [&](size_t bytes) {
    char* p = ws + o;
    o = (o + bytes + 255) & ~(size_t)255;
    return p;
  };
  const size_t NCb = (size_t)NN * 256 * 4;
  float* h = (float*)take(NCb);
  float* pm = (float*)take(NCb);
  float* V = (float*)take(NCb);  // aliased as R after aggregation
  float* comb = (float*)take(NCb);
  float* Wall = (float*)take(256 * 256 * 4);
  float* ball = (float*)take(256 * 4);
  int* cnt = (int*)take((size_t)NN * 4);
  int* rs = (int*)take((size_t)(NN + 1) * 4);
  int* ncnt = (int*)take((size_t)NN * 4);
  int* csr = (int*)take((size_t)EE * 4);
  float* R = V;
  float* Zb = out;  // d_out used as scratch for Z; fully overwritten by add_kernel

  hipMemsetAsync(cnt, 0, (size_t)NN * 4, stream);
  hipMemsetAsync(ncnt, 0, (size_t)NN * 4, stream);
  count_kernel<<<(EE + 255) / 256, 256, 0, stream>>>(edst, cnt);
  scan_kernel<<<1, 1024, 0, stream>>>(cnt, rs);
  fill_kernel<<<(EE + 255) / 256, 256, 0, stream>>>(edst, rs, ncnt, csr);
  wall_kernel<<<256, 256, 0, stream>>>(Wv, Wd, Wall);
  ball_kernel<<<1, 256, 0, stream>>>(bv, Wd, bd, ball);

  proj_kernel<<<dim3(4, 782), 256, 0, stream>>>(node_feats, role, Wq, bq, We, be, Wc, bc, h, pm);

  for (int layer = 0; layer < NL; ++layer) {
    vgemm_kernel<<<dim3(4, 782), 256, 0, stream>>>(h, Wall, ball, V);
    agg_kernel<<<(NN + 3) / 4, 256, 0, stream>>>(csr, rs, esrc, ew, V, comb);
    gru_rz_kernel<<<dim3(8, 782), 256, 0, stream>>>(comb, pm, Wih, Whh, bih, bhh, R, Zb);
    gru_n_kernel<<<NN / 16, 256, 0, stream>>>(comb, pm, Wih, Whh, bih, bhh, R, Zb);
    wo_ln_kernel<<<NN / 16, 256, 0, stream>>>(comb, Wo, bo, h, lnw + layer * 256, lnb + layer * 256);
  }

  add_kernel<<<(NN * 256 / 4 + 255) / 256, 256, 0, stream>>>(h, pm, out);
}

// Round 2
// 2279.495 us; speedup vs baseline: 1.7979x; 1.7979x over previous
//
#include <hip/hip_runtime.h>
#include <math.h>

#define NN 50000
#define EE 1600000
#define IND 300
#define KPAD 320
#define NL 3
#define NBLK 785

typedef unsigned short u16;
typedef __attribute__((ext_vector_type(8))) short short8;
typedef __attribute__((ext_vector_type(4))) float floatx4;

__device__ __forceinline__ float b2f(u16 u) {
  union { unsigned i; float f; } v; v.i = ((unsigned)u) << 16; return v.f;
}
__device__ __forceinline__ u16 f2b(float f) {
  union { unsigned i; float f; } v; v.f = f;
  unsigned b = v.i; b += 0x7fffu + ((b >> 16) & 1u);
  return (u16)(b >> 16);
}
__device__ __forceinline__ float sigf(float x) { return 1.0f / (1.0f + __expf(-x)); }

// ============================ CSR build ============================
__global__ void count_kernel(const int* __restrict__ dst, int* __restrict__ cnt) {
  int e = blockIdx.x * 256 + threadIdx.x;
  if (e < EE) atomicAdd(&cnt[dst[e]], 1);
}

__global__ void scan_kernel(const int* __restrict__ cnt, int* __restrict__ rs) {
  __shared__ int wsum[16], wpre[16];
  __shared__ int carryS, totS;
  const int t = threadIdx.x;
  const int l = t & 63, wid = t >> 6;
  if (t == 0) carryS = 0;
  __syncthreads();
  for (int base = 0; base < NN; base += 1024) {
    const int carry = carryS;
    const int i = base + t;
    int v = (i < NN) ? cnt[i] : 0;
    int x = v;
    #pragma unroll
    for (int off = 1; off < 64; off <<= 1) {
      int y = __shfl_up(x, off);
      if (l >= off) x += y;
    }
    if (l == 63) wsum[wid] = x;
    __syncthreads();
    if (t < 16) {
      int s = wsum[t];
      int xx = s;
      #pragma unroll
      for (int off = 1; off < 16; off <<= 1) {
        int y = __shfl_up(xx, off);
        if (t >= off) xx += y;
      }
      wpre[t] = xx - s;
      if (t == 15) totS = xx;
    }
    __syncthreads();
    if (i < NN) rs[i] = carry + wpre[wid] + (x - v);
    __syncthreads();
    if (t == 0) carryS = carry + totS;
    __syncthreads();
  }
  if (t == 0) rs[NN] = carryS;
}

__global__ void fill_kernel(const int* __restrict__ dst, const int* __restrict__ rs,
                            int* __restrict__ ncnt, int* __restrict__ csr) {
  int e = blockIdx.x * 256 + threadIdx.x;
  if (e < EE) {
    int d = dst[e];
    int p = atomicAdd(&ncnt[d], 1);
    csr[rs[d] + p] = e;
  }
}

// ============================ role bucketing ============================
__global__ void role_count(const int* __restrict__ role, int* __restrict__ cnt3) {
  int i = blockIdx.x * 256 + threadIdx.x;
  if (i < NN) atomicAdd(&cnt3[role[i]], 1);
}

__global__ void role_plan(const int* __restrict__ cnt3, int* __restrict__ pbase,
                          int* __restrict__ blkrole) {
  __shared__ int pb[4];
  if (threadIdx.x == 0) {
    pb[0] = 0;
    for (int b = 0; b < 3; ++b) pb[b + 1] = pb[b] + (((cnt3[b] + 63) >> 6) << 6);
    for (int b = 0; b < 4; ++b) pbase[b] = pb[b];
  }
  __syncthreads();
  for (int blk = threadIdx.x; blk < NBLK; blk += 256) {
    int m0 = blk * 64;
    int r = -1;
    for (int b = 0; b < 3; ++b)
      if (m0 >= pb[b] && m0 < pb[b + 1]) r = b;
    blkrole[blk] = r;
  }
}

__global__ void role_fill(const int* __restrict__ role, const int* __restrict__ pbase,
                          int* __restrict__ pos3, int* __restrict__ perm) {
  int i = blockIdx.x * 256 + threadIdx.x;
  if (i < NN) {
    int r = role[i];
    int p = atomicAdd(&pos3[r], 1);
    perm[pbase[r] + p] = i;
  }
}

// ============================ weight prep ============================
__global__ void xcast_kernel(const float* __restrict__ X, u16* __restrict__ Xb) {
  size_t i = (size_t)blockIdx.x * 256 + threadIdx.x;
  if (i >= (size_t)NN * KPAD) return;
  int r = (int)(i / KPAD), k = (int)(i % KPAD);
  Xb[i] = (k < IND) ? f2b(X[(size_t)r * IND + k]) : (u16)0;
}

__global__ void wt3_kernel(const float* __restrict__ Wq, const float* __restrict__ We,
                           const float* __restrict__ Wc, u16* __restrict__ Wqt,
                           u16* __restrict__ Wet, u16* __restrict__ Wct) {
  int n = blockIdx.x;
  int which = blockIdx.y;
  const float* W = (which == 0) ? Wq : (which == 1) ? We : Wc;
  u16* Wt = (which == 0) ? Wqt : (which == 1) ? Wet : Wct;
  for (int k = threadIdx.x; k < KPAD; k += 256)
    Wt[(size_t)n * KPAD + k] = (k < IND) ? f2b(W[(size_t)k * 256 + n]) : (u16)0;
}

// Wallt[c][i] = sum_m Wv[hd][i][m] * Wd[m][j], c = hd*64+j  (transposed, bf16)
__global__ void wallt_kernel(const float* __restrict__ Wv, const float* __restrict__ Wd,
                             u16* __restrict__ Wallt) {
  int i = blockIdx.x;
  int c = threadIdx.x;
  int hd = c >> 6, j = c & 63;
  const float* wv = &Wv[hd * (256 * 64) + i * 64];
  float s = 0.f;
  #pragma unroll
  for (int m = 0; m < 64; ++m) s = fmaf(wv[m], Wd[m * 64 + j], s);
  Wallt[(size_t)c * 256 + i] = f2b(s);
}

__global__ void ball_kernel(const float* __restrict__ bv, const float* __restrict__ Wd,
                            const float* __restrict__ bd, float* __restrict__ ball) {
  int c = threadIdx.x;
  int hd = c >> 6, j = c & 63;
  float s = bd[j];
  #pragma unroll
  for (int m = 0; m < 64; ++m) s = fmaf(bv[hd * 64 + m], Wd[m * 64 + j], s);
  ball[c] = s;
}

__global__ void wot_kernel(const float* __restrict__ Wo, u16* __restrict__ Wot) {
  int n = blockIdx.x;
  int k = threadIdx.x;
  Wot[(size_t)n * 256 + k] = f2b(Wo[(size_t)k * 256 + n]);
}

__global__ void castbf_kernel(const float* __restrict__ s, u16* __restrict__ d, int n) {
  int i = blockIdx.x * 256 + threadIdx.x;
  if (i < n) d[i] = f2b(s[i]);
}

// ============================ MFMA GEMM common ============================
#define GEMM_PROLOG \
  __shared__ __align__(16) u16 As[64][72]; \
  __shared__ __align__(16) u16 Bs[64][72]; \
  const int t = threadIdx.x; \
  const int lane = t & 63; \
  const int wv_ = t >> 6; \
  const int wr = wv_ >> 1, wc = wv_ & 1; \
  const int l15 = lane & 15, l4 = lane >> 4; \
  const int srow = t >> 2; \
  const int scol = (t & 3) << 4;

#define STAGE_A(AG, ASTRIDE, VALID, ROWIDX, K0) { \
  int4 v0 = {0, 0, 0, 0}, v1 = {0, 0, 0, 0}; \
  if (VALID) { \
    const int4* p_ = (const int4*)&(AG)[(size_t)(ROWIDX) * (ASTRIDE) + (K0) + scol]; \
    v0 = p_[0]; v1 = p_[1]; \
  } \
  *(int4*)&As[srow][scol] = v0; \
  *(int4*)&As[srow][scol + 8] = v1; }

#define STAGE_B(BG, BSTRIDE, ROWIDX, K0) { \
  const int4* p_ = (const int4*)&(BG)[(size_t)(ROWIDX) * (BSTRIDE) + (K0) + scol]; \
  *(int4*)&Bs[srow][scol] = p_[0]; \
  *(int4*)&Bs[srow][scol + 8] = p_[1]; }

#define MFMA_STEP(ACC) { \
  _Pragma("unroll") \
  for (int kc = 0; kc < 2; ++kc) { \
    short8 a0_ = *(const short8*)&As[wr * 32 + 0 + l15][kc * 32 + l4 * 8]; \
    short8 a1_ = *(const short8*)&As[wr * 32 + 16 + l15][kc * 32 + l4 * 8]; \
    short8 b0_ = *(const short8*)&Bs[wc * 32 + 0 + l15][kc * 32 + l4 * 8]; \
    short8 b1_ = *(const short8*)&Bs[wc * 32 + 16 + l15][kc * 32 + l4 * 8]; \
    ACC[0][0] = __builtin_amdgcn_mfma_f32_16x16x32_bf16(a0_, b0_, ACC[0][0], 0, 0, 0); \
    ACC[0][1] = __builtin_amdgcn_mfma_f32_16x16x32_bf16(a0_, b1_, ACC[0][1], 0, 0, 0); \
    ACC[1][0] = __builtin_amdgcn_mfma_f32_16x16x32_bf16(a1_, b0_, ACC[1][0], 0, 0, 0); \
    ACC[1][1] = __builtin_amdgcn_mfma_f32_16x16x32_bf16(a1_, b1_, ACC[1][1], 0, 0, 0); \
  } }

// ============================ proj (role-bucketed, gathered rows) ============================
__global__ __launch_bounds__(256) void proj_mfma(
    const u16* __restrict__ Xb, const int* __restrict__ perm,
    const int* __restrict__ blkrole,
    const u16* __restrict__ Wqt, const u16* __restrict__ Wet, const u16* __restrict__ Wct,
    const float* __restrict__ bq, const float* __restrict__ be, const float* __restrict__ bc,
    u16* __restrict__ h, u16* __restrict__ pm) {
  const int brole = blkrole[blockIdx.y];
  if (brole < 0) return;
  GEMM_PROLOG
  const int m0 = blockIdx.y * 64;
  const int n0 = blockIdx.x * 64;
  const u16* Bt = (brole == 0) ? Wqt : (brole == 1) ? Wet : Wct;
  const float* bb = (brole == 0) ? bq : (brole == 1) ? be : bc;
  const int prow = perm[m0 + srow];
  floatx4 acc[2][2] = {};
  for (int k0 = 0; k0 < KPAD; k0 += 64) {
    STAGE_A(Xb, KPAD, prow >= 0, prow, k0)
    STAGE_B(Bt, KPAD, n0 + srow, k0)
    __syncthreads();
    MFMA_STEP(acc)
    __syncthreads();
  }
  #pragma unroll
  for (int m = 0; m < 2; ++m)
    #pragma unroll
    for (int reg = 0; reg < 4; ++reg) {
      int gr = m0 + wr * 32 + m * 16 + l4 * 4 + reg;
      int pr = perm[gr];
      if (pr >= 0) {
        #pragma unroll
        for (int n = 0; n < 2; ++n) {
          int c = n0 + wc * 32 + n * 16 + l15;
          float vo = fmaxf(acc[m][n][reg] + bb[c], 0.f);
          u16 ub = f2b(vo);
          h[(size_t)pr * 256 + c] = ub;
          pm[(size_t)pr * 256 + c] = ub;
        }
      }
    }
}

// ============================ V = h @ Wall + ball ============================
__global__ __launch_bounds__(256) void vgemm_mfma(
    const u16* __restrict__ A, const u16* __restrict__ Bt,
    const float* __restrict__ bias, u16* __restrict__ C) {
  GEMM_PROLOG
  const int m0 = blockIdx.y * 64;
  const int n0 = blockIdx.x * 64;
  const int ar = m0 + srow;
  floatx4 acc[2][2] = {};
  for (int k0 = 0; k0 < 256; k0 += 64) {
    STAGE_A(A, 256, ar < NN, ar, k0)
    STAGE_B(Bt, 256, n0 + srow, k0)
    __syncthreads();
    MFMA_STEP(acc)
    __syncthreads();
  }
  #pragma unroll
  for (int m = 0; m < 2; ++m)
    #pragma unroll
    for (int reg = 0; reg < 4; ++reg) {
      int gr = m0 + wr * 32 + m * 16 + l4 * 4 + reg;
      if (gr < NN) {
        #pragma unroll
        for (int n = 0; n < 2; ++n) {
          int c = n0 + wc * 32 + n * 16 + l15;
          C[(size_t)gr * 256 + c] = f2b(acc[m][n][reg] + bias[c]);
        }
      }
    }
}

// ============================ aggregation ============================
__global__ __launch_bounds__(256) void agg_kernel(
    const int* __restrict__ csr, const int* __restrict__ rs,
    const int* __restrict__ esrc, const float* __restrict__ ew,
    const u16* __restrict__ V, u16* __restrict__ comb) {
  int n = blockIdx.x * 4 + (threadIdx.x >> 6);
  int l = threadIdx.x & 63;
  if (n >= NN) return;
  int s = rs[n], e = rs[n + 1];
  float a0 = 0.f, a1 = 0.f, a2 = 0.f, a3 = 0.f;
  for (int j = s; j < e; ++j) {
    int eid = csr[j];
    int src = esrc[eid];
    float w = ew[eid];
    ushort4 v = *(const ushort4*)&V[(size_t)src * 256 + l * 4];
    a0 = fmaf(w, b2f(v.x), a0);
    a1 = fmaf(w, b2f(v.y), a1);
    a2 = fmaf(w, b2f(v.z), a2);
    a3 = fmaf(w, b2f(v.w), a3);
  }
  ushort4 o;
  o.x = f2b(a0); o.y = f2b(a1); o.z = f2b(a2); o.w = f2b(a3);
  *(ushort4*)&comb[(size_t)n * 256 + l * 4] = o;
}

// ============================ GRU r,z gates ============================
__global__ __launch_bounds__(256) void grurz_mfma(
    const u16* __restrict__ comb, const u16* __restrict__ pmc,
    const u16* __restrict__ Wiht, const u16* __restrict__ Whht,
    const float* __restrict__ bih, const float* __restrict__ bhh,
    u16* __restrict__ R, u16* __restrict__ Z) {
  GEMM_PROLOG
  const int m0 = blockIdx.y * 64;
  const int j0 = blockIdx.x * 64;  // 0..448
  const int ar = m0 + srow;
  floatx4 acc[2][2] = {};
  #pragma unroll
  for (int p = 0; p < 2; ++p) {
    const u16* Ag = p ? pmc : comb;
    const u16* Bt = p ? Whht : Wiht;
    for (int k0 = 0; k0 < 256; k0 += 64) {
      STAGE_A(Ag, 256, ar < NN, ar, k0)
      STAGE_B(Bt, 256, j0 + srow, k0)
      __syncthreads();
      MFMA_STEP(acc)
      __syncthreads();
    }
  }
  #pragma unroll
  for (int m = 0; m < 2; ++m)
    #pragma unroll
    for (int reg = 0; reg < 4; ++reg) {
      int gr = m0 + wr * 32 + m * 16 + l4 * 4 + reg;
      if (gr < NN) {
        #pragma unroll
        for (int n = 0; n < 2; ++n) {
          int j = j0 + wc * 32 + n * 16 + l15;
          float g = sigf(acc[m][n][reg] + bih[j] + bhh[j]);
          if (j < 256) R[(size_t)gr * 256 + j] = f2b(g);
          else         Z[(size_t)gr * 256 + (j - 256)] = f2b(g);
        }
      }
    }
}

// ============================ GRU n-gate + state update ============================
__global__ __launch_bounds__(256) void grun_mfma(
    const u16* __restrict__ comb, const u16* __restrict__ pmc,
    const u16* __restrict__ Wiht, const u16* __restrict__ Whht,
    const float* __restrict__ bih, const float* __restrict__ bhh,
    const u16* __restrict__ R, const u16* __restrict__ Z,
    u16* __restrict__ pmn) {
  GEMM_PROLOG
  const int m0 = blockIdx.y * 64;
  const int n0 = blockIdx.x * 64;
  const int ar = m0 + srow;
  floatx4 ai[2][2] = {};
  floatx4 ah[2][2] = {};
  for (int k0 = 0; k0 < 256; k0 += 64) {
    STAGE_A(comb, 256, ar < NN, ar, k0)
    STAGE_B(Wiht, 256, 512 + n0 + srow, k0)
    __syncthreads();
    MFMA_STEP(ai)
    __syncthreads();
  }
  for (int k0 = 0; k0 < 256; k0 += 64) {
    STAGE_A(pmc, 256, ar < NN, ar, k0)
    STAGE_B(Whht, 256, 512 + n0 + srow, k0)
    __syncthreads();
    MFMA_STEP(ah)
    __syncthreads();
  }
  #pragma unroll
  for (int m = 0; m < 2; ++m)
    #pragma unroll
    for (int reg = 0; reg < 4; ++reg) {
      int gr = m0 + wr * 32 + m * 16 + l4 * 4 + reg;
      if (gr < NN) {
        #pragma unroll
        for (int n = 0; n < 2; ++n) {
          int c = n0 + wc * 32 + n * 16 + l15;
          float i_n = ai[m][n][reg] + bih[512 + c];
          float h_n = ah[m][n][reg] + bhh[512 + c];
          float rg = b2f(R[(size_t)gr * 256 + c]);
          float z = b2f(Z[(size_t)gr * 256 + c]);
          float po = b2f(pmc[(size_t)gr * 256 + c]);
          float nn2 = tanhf(i_n + rg * h_n);
          pmn[(size_t)gr * 256 + c] = f2b((1.f - z) * nn2 + z * po);
        }
      }
    }
}

// ============================ tmp = comb @ Wo + bo + h ============================
__global__ __launch_bounds__(256) void wo_mfma(
    const u16* __restrict__ comb, const u16* __restrict__ Wot,
    const float* __restrict__ bo, const u16* __restrict__ h,
    u16* __restrict__ tmp) {
  GEMM_PROLOG
  const int m0 = blockIdx.y * 64;
  const int n0 = blockIdx.x * 64;
  const int ar = m0 + srow;
  floatx4 acc[2][2] = {};
  for (int k0 = 0; k0 < 256; k0 += 64) {
    STAGE_A(comb, 256, ar < NN, ar, k0)
    STAGE_B(Wot, 256, n0 + srow, k0)
    __syncthreads();
    MFMA_STEP(acc)
    __syncthreads();
  }
  #pragma unroll
  for (int m = 0; m < 2; ++m)
    #pragma unroll
    for (int reg = 0; reg < 4; ++reg) {
      int gr = m0 + wr * 32 + m * 16 + l4 * 4 + reg;
      if (gr < NN) {
        #pragma unroll
        for (int n = 0; n < 2; ++n) {
          int c = n0 + wc * 32 + n * 16 + l15;
          float v = acc[m][n][reg] + bo[c] + b2f(h[(size_t)gr * 256 + c]);
          tmp[(size_t)gr * 256 + c] = f2b(v);
        }
      }
    }
}

// ============================ LayerNorm (row-wise) ============================
__global__ __launch_bounds__(256) void ln_kernel(
    const u16* __restrict__ tmp, u16* __restrict__ h,
    const float* __restrict__ lnw, const float* __restrict__ lnb) {
  int n = blockIdx.x * 4 + (threadIdx.x >> 6);
  int l = threadIdx.x & 63;
  if (n >= NN) return;
  ushort4 v = *(const ushort4*)&tmp[(size_t)n * 256 + l * 4];
  float x0 = b2f(v.x), x1 = b2f(v.y), x2 = b2f(v.z), x3 = b2f(v.w);
  float s = x0 + x1 + x2 + x3;
  #pragma unroll
  for (int off = 1; off < 64; off <<= 1) s += __shfl_xor(s, off);
  float mu = s * (1.f / 256.f);
  float d0 = x0 - mu, d1 = x1 - mu, d2 = x2 - mu, d3 = x3 - mu;
  float vs = d0 * d0 + d1 * d1 + d2 * d2 + d3 * d3;
  #pragma unroll
  for (int off = 1; off < 64; off <<= 1) vs += __shfl_xor(vs, off);
  float inv = rsqrtf(vs * (1.f / 256.f) + 1e-5f);
  int c = l * 4;
  ushort4 o;
  o.x = f2b(d0 * inv * lnw[c + 0] + lnb[c + 0]);
  o.y = f2b(d1 * inv * lnw[c + 1] + lnb[c + 1]);
  o.z = f2b(d2 * inv * lnw[c + 2] + lnb[c + 2]);
  o.w = f2b(d3 * inv * lnw[c + 3] + lnb[c + 3]);
  *(ushort4*)&h[(size_t)n * 256 + c] = o;
}

// ============================ out = h + pm (f32) ============================
__global__ void add_out(const u16* __restrict__ a, const u16* __restrict__ b,
                        float* __restrict__ o) {
  size_t i = (size_t)blockIdx.x * 256 + threadIdx.x;
  if (i < (size_t)NN * 64) {
    ushort4 x = *(const ushort4*)&a[i * 4];
    ushort4 y = *(const ushort4*)&b[i * 4];
    float4 r;
    r.x = b2f(x.x) + b2f(y.x);
    r.y = b2f(x.y) + b2f(y.y);
    r.z = b2f(x.z) + b2f(y.z);
    r.w = b2f(x.w) + b2f(y.w);
    *(float4*)&o[i * 4] = r;
  }
}

extern "C" void kernel_launch(void* const* d_in, const int* in_sizes, int n_in,
                              void* d_out, int out_size, void* d_ws, size_t ws_size,
                              hipStream_t stream) {
  const float* node_feats = (const float*)d_in[0];
  const int* role = (const int*)d_in[1];
  const int* esrc = (const int*)d_in[2];
  const int* edst = (const int*)d_in[3];
  const float* ew = (const float*)d_in[4];
  const float* Wq = (const float*)d_in[5];
  const float* bq = (const float*)d_in[6];
  const float* We = (const float*)d_in[7];
  const float* be = (const float*)d_in[8];
  const float* Wc = (const float*)d_in[9];
  const float* bc = (const float*)d_in[10];
  const float* Wv = (const float*)d_in[11];
  const float* bv = (const float*)d_in[12];
  const float* Wd = (const float*)d_in[13];
  const float* bd = (const float*)d_in[14];
  const float* Wo = (const float*)d_in[15];
  const float* bo = (const float*)d_in[16];
  const float* Wih = (const float*)d_in[17];
  const float* Whh = (const float*)d_in[18];
  const float* bih = (const float*)d_in[19];
  const float* bhh = (const float*)d_in[20];
  const float* lnw = (const float*)d_in[21];
  const float* lnb = (const float*)d_in[22];
  float* out = (float*)d_out;

  char* ws = (char*)d_ws;
  size_t off = 0;
  auto take = [&](size_t bytes) {
    char* p = ws + off;
    off = (off + bytes + 255) & ~(size_t)255;
    return p;
  };
  const size_t NC2 = (size_t)NN * 256 * 2;
  u16* Xb = (u16*)take((size_t)NN * KPAD * 2);
  u16* h = (u16*)take(NC2);
  u16* pm0 = (u16*)take(NC2);
  u16* pm1 = (u16*)take(NC2);
  u16* V = (u16*)take(NC2);   // aliased as R after agg consumes it
  u16* comb = (u16*)take(NC2);
  u16* Z = (u16*)take(NC2);
  u16* tmp = (u16*)take(NC2);
  u16* Wqt = (u16*)take((size_t)256 * KPAD * 2);
  u16* Wet = (u16*)take((size_t)256 * KPAD * 2);
  u16* Wct = (u16*)take((size_t)256 * KPAD * 2);
  u16* Wallt = (u16*)take((size_t)256 * 256 * 2);
  u16* Wot = (u16*)take((size_t)256 * 256 * 2);
  u16* Wiht = (u16*)take((size_t)768 * 256 * 2);
  u16* Whht = (u16*)take((size_t)768 * 256 * 2);
  float* ball = (float*)take(256 * 4);
  int* cnt = (int*)take((size_t)NN * 4);
  int* rs = (int*)take((size_t)(NN + 1) * 4);
  int* ncnt = (int*)take((size_t)NN * 4);
  int* csr = (int*)take((size_t)EE * 4);
  int* cnt3 = (int*)take(16);
  int* pos3 = (int*)take(16);
  int* pbase = (int*)take(16);
  int* blkrole = (int*)take((size_t)NBLK * 4);
  int* perm = (int*)take((size_t)NBLK * 64 * 4);
  u16* R = V;

  hipMemsetAsync(cnt, 0, (size_t)NN * 4, stream);
  hipMemsetAsync(ncnt, 0, (size_t)NN * 4, stream);
  hipMemsetAsync(cnt3, 0, 16, stream);
  hipMemsetAsync(pos3, 0, 16, stream);
  hipMemsetAsync(perm, 0xFF, (size_t)NBLK * 64 * 4, stream);

  count_kernel<<<(EE + 255) / 256, 256, 0, stream>>>(edst, cnt);
  scan_kernel<<<1, 1024, 0, stream>>>(cnt, rs);
  fill_kernel<<<(EE + 255) / 256, 256, 0, stream>>>(edst, rs, ncnt, csr);

  role_count<<<(NN + 255) / 256, 256, 0, stream>>>(role, cnt3);
  role_plan<<<1, 256, 0, stream>>>(cnt3, pbase, blkrole);
  role_fill<<<(NN + 255) / 256, 256, 0, stream>>>(role, pbase, pos3, perm);

  xcast_kernel<<<(int)(((size_t)NN * KPAD + 255) / 256), 256, 0, stream>>>(node_feats, Xb);
  wt3_kernel<<<dim3(256, 3), 256, 0, stream>>>(Wq, We, Wc, Wqt, Wet, Wct);
  wallt_kernel<<<256, 256, 0, stream>>>(Wv, Wd, Wallt);
  ball_kernel<<<1, 256, 0, stream>>>(bv, Wd, bd, ball);
  wot_kernel<<<256, 256, 0, stream>>>(Wo, Wot);
  castbf_kernel<<<(768 * 256 + 255) / 256, 256, 0, stream>>>(Wih, Wiht, 768 * 256);
  castbf_kernel<<<(768 * 256 + 255) / 256, 256, 0, stream>>>(Whh, Whht, 768 * 256);

  proj_mfma<<<dim3(4, NBLK), 256, 0, stream>>>(Xb, perm, blkrole, Wqt, Wet, Wct,
                                               bq, be, bc, h, pm0);

  u16* pmc = pm0;
  u16* pmn = pm1;
  const int MB = (NN + 63) / 64;  // 782
  for (int layer = 0; layer < NL; ++layer) {
    vgemm_mfma<<<dim3(4, MB), 256, 0, stream>>>(h, Wallt, ball, V);
    agg_kernel<<<(NN + 3) / 4, 256, 0, stream>>>(csr, rs, esrc, ew, V, comb);
    grurz_mfma<<<dim3(8, MB), 256, 0, stream>>>(comb, pmc, Wiht, Whht, bih, bhh, R, Z);
    grun_mfma<<<dim3(4, MB), 256, 0, stream>>>(comb, pmc, Wiht, Whht, bih, bhh, R, Z, pmn);
    wo_mfma<<<dim3(4, MB), 256, 0, stream>>>(comb, Wot, bo, h, tmp);
    ln_kernel<<<(NN + 3) / 4, 256, 0, stream>>>(tmp, h, lnw + layer * 256, lnb + layer * 256);
    u16* sw = pmc; pmc = pmn; pmn = sw;
  }

  add_out<<<(int)(((size_t)NN * 64 + 255) / 256), 256, 0, stream>>>(h, pmc, out);
}

// Round 3
// 1638.342 us; speedup vs baseline: 2.5015x; 1.3913x over previous
//
#include <hip/hip_runtime.h>
#include <math.h>

#define NN 50000
#define EE 1600000
#define IND 300
#define KPAD 320
#define NL 3
#define NBLK 785

typedef unsigned short u16;
typedef __attribute__((ext_vector_type(8))) short short8;
typedef __attribute__((ext_vector_type(4))) float floatx4;

__device__ __forceinline__ float b2f(u16 u) {
  union { unsigned i; float f; } v; v.i = ((unsigned)u) << 16; return v.f;
}
__device__ __forceinline__ u16 f2b(float f) {
  union { unsigned i; float f; } v; v.f = f;
  unsigned b = v.i; b += 0x7fffu + ((b >> 16) & 1u);
  return (u16)(b >> 16);
}
__device__ __forceinline__ float sigf(float x) { return 1.0f / (1.0f + __expf(-x)); }

// ============================ CSR build ============================
__global__ void count_kernel(const int* __restrict__ dst, int* __restrict__ cnt) {
  int e = blockIdx.x * 256 + threadIdx.x;
  if (e < EE) atomicAdd(&cnt[dst[e]], 1);
}

__global__ void scan_kernel(const int* __restrict__ cnt, int* __restrict__ rs) {
  __shared__ int wsum[16], wpre[16];
  __shared__ int carryS, totS;
  const int t = threadIdx.x;
  const int l = t & 63, wid = t >> 6;
  if (t == 0) carryS = 0;
  __syncthreads();
  for (int base = 0; base < NN; base += 1024) {
    const int carry = carryS;
    const int i = base + t;
    int v = (i < NN) ? cnt[i] : 0;
    int x = v;
    #pragma unroll
    for (int off = 1; off < 64; off <<= 1) {
      int y = __shfl_up(x, off);
      if (l >= off) x += y;
    }
    if (l == 63) wsum[wid] = x;
    __syncthreads();
    if (t < 16) {
      int s = wsum[t];
      int xx = s;
      #pragma unroll
      for (int off = 1; off < 16; off <<= 1) {
        int y = __shfl_up(xx, off);
        if (t >= off) xx += y;
      }
      wpre[t] = xx - s;
      if (t == 15) totS = xx;
    }
    __syncthreads();
    if (i < NN) rs[i] = carry + wpre[wid] + (x - v);
    __syncthreads();
    if (t == 0) carryS = carry + totS;
    __syncthreads();
  }
  if (t == 0) rs[NN] = carryS;
}

__global__ void fill_kernel(const int* __restrict__ dst, const int* __restrict__ rs,
                            int* __restrict__ ncnt, int* __restrict__ csr) {
  int e = blockIdx.x * 256 + threadIdx.x;
  if (e < EE) {
    int d = dst[e];
    int p = atomicAdd(&ncnt[d], 1);
    csr[rs[d] + p] = e;
  }
}

// ============================ role bucketing (contention-free) ============================
__global__ void role_count(const int* __restrict__ role, int* __restrict__ cnt3) {
  __shared__ int lc[3];
  if (threadIdx.x < 3) lc[threadIdx.x] = 0;
  __syncthreads();
  int i = blockIdx.x * 256 + threadIdx.x;
  if (i < NN) atomicAdd(&lc[role[i]], 1);
  __syncthreads();
  if (threadIdx.x < 3) atomicAdd(&cnt3[threadIdx.x], lc[threadIdx.x]);
}

__global__ void role_plan(const int* __restrict__ cnt3, int* __restrict__ pbase,
                          int* __restrict__ blkrole) {
  __shared__ int pb[4];
  if (threadIdx.x == 0) {
    pb[0] = 0;
    for (int b = 0; b < 3; ++b) pb[b + 1] = pb[b] + (((cnt3[b] + 63) >> 6) << 6);
    for (int b = 0; b < 4; ++b) pbase[b] = pb[b];
  }
  __syncthreads();
  for (int blk = threadIdx.x; blk < NBLK; blk += 256) {
    int m0 = blk * 64;
    int r = -1;
    for (int b = 0; b < 3; ++b)
      if (m0 >= pb[b] && m0 < pb[b + 1]) r = b;
    blkrole[blk] = r;
  }
}

// block-level LDS histogram -> 3 global atomics per block -> local rank scatter
__global__ void role_fill(const int* __restrict__ role, const int* __restrict__ pbase,
                          int* __restrict__ pos3, int* __restrict__ perm) {
  __shared__ int lcnt[3], lbase[3];
  int i = blockIdx.x * 256 + threadIdx.x;
  if (threadIdx.x < 3) lcnt[threadIdx.x] = 0;
  __syncthreads();
  int r = 0, lr = 0;
  bool valid = (i < NN);
  if (valid) {
    r = role[i];
    lr = atomicAdd(&lcnt[r], 1);
  }
  __syncthreads();
  if (threadIdx.x < 3) lbase[threadIdx.x] = atomicAdd(&pos3[threadIdx.x], lcnt[threadIdx.x]);
  __syncthreads();
  if (valid) perm[pbase[r] + lbase[r] + lr] = i;
}

// ============================ weight prep ============================
__global__ void xcast_kernel(const float* __restrict__ X, u16* __restrict__ Xb) {
  size_t i = (size_t)blockIdx.x * 256 + threadIdx.x;
  if (i >= (size_t)NN * KPAD) return;
  int r = (int)(i / KPAD), k = (int)(i % KPAD);
  Xb[i] = (k < IND) ? f2b(X[(size_t)r * IND + k]) : (u16)0;
}

__global__ void wt3_kernel(const float* __restrict__ Wq, const float* __restrict__ We,
                           const float* __restrict__ Wc, u16* __restrict__ Wqt,
                           u16* __restrict__ Wet, u16* __restrict__ Wct) {
  int n = blockIdx.x;
  int which = blockIdx.y;
  const float* W = (which == 0) ? Wq : (which == 1) ? We : Wc;
  u16* Wt = (which == 0) ? Wqt : (which == 1) ? Wet : Wct;
  for (int k = threadIdx.x; k < KPAD; k += 256)
    Wt[(size_t)n * KPAD + k] = (k < IND) ? f2b(W[(size_t)k * 256 + n]) : (u16)0;
}

// Wallt[c][i] = sum_m Wv[hd][i][m] * Wd[m][j], c = hd*64+j  (transposed, bf16)
__global__ void wallt_kernel(const float* __restrict__ Wv, const float* __restrict__ Wd,
                             u16* __restrict__ Wallt) {
  int i = blockIdx.x;
  int c = threadIdx.x;
  int hd = c >> 6, j = c & 63;
  const float* wv = &Wv[hd * (256 * 64) + i * 64];
  float s = 0.f;
  #pragma unroll
  for (int m = 0; m < 64; ++m) s = fmaf(wv[m], Wd[m * 64 + j], s);
  Wallt[(size_t)c * 256 + i] = f2b(s);
}

__global__ void ball_kernel(const float* __restrict__ bv, const float* __restrict__ Wd,
                            const float* __restrict__ bd, float* __restrict__ ball) {
  int c = threadIdx.x;
  int hd = c >> 6, j = c & 63;
  float s = bd[j];
  #pragma unroll
  for (int m = 0; m < 64; ++m) s = fmaf(bv[hd * 64 + m], Wd[m * 64 + j], s);
  ball[c] = s;
}

__global__ void wot_kernel(const float* __restrict__ Wo, u16* __restrict__ Wot) {
  int n = blockIdx.x;
  int k = threadIdx.x;
  Wot[(size_t)n * 256 + k] = f2b(Wo[(size_t)k * 256 + n]);
}

// casts Wih then Whh (n = 2 * 768*256)
__global__ void castbf2_kernel(const float* __restrict__ s0, const float* __restrict__ s1,
                               u16* __restrict__ d0, u16* __restrict__ d1) {
  int i = blockIdx.x * 256 + threadIdx.x;
  const int n = 768 * 256;
  if (i < n) d0[i] = f2b(s0[i]);
  else if (i < 2 * n) d1[i - n] = f2b(s1[i - n]);
}

// ============================ MFMA GEMM common ============================
#define GEMM_PROLOG \
  __shared__ __align__(16) u16 As[64][72]; \
  __shared__ __align__(16) u16 Bs[64][72]; \
  const int t = threadIdx.x; \
  const int lane = t & 63; \
  const int wv_ = t >> 6; \
  const int wr = wv_ >> 1, wc = wv_ & 1; \
  const int l15 = lane & 15, l4 = lane >> 4; \
  const int srow = t >> 2; \
  const int scol = (t & 3) << 4;

#define STAGE_A(AG, ASTRIDE, VALID, ROWIDX, K0) { \
  int4 v0 = {0, 0, 0, 0}, v1 = {0, 0, 0, 0}; \
  if (VALID) { \
    const int4* p_ = (const int4*)&(AG)[(size_t)(ROWIDX) * (ASTRIDE) + (K0) + scol]; \
    v0 = p_[0]; v1 = p_[1]; \
  } \
  *(int4*)&As[srow][scol] = v0; \
  *(int4*)&As[srow][scol + 8] = v1; }

#define STAGE_B(BG, BSTRIDE, ROWIDX, K0) { \
  const int4* p_ = (const int4*)&(BG)[(size_t)(ROWIDX) * (BSTRIDE) + (K0) + scol]; \
  *(int4*)&Bs[srow][scol] = p_[0]; \
  *(int4*)&Bs[srow][scol + 8] = p_[1]; }

#define MFMA_STEP(ACC) { \
  _Pragma("unroll") \
  for (int kc = 0; kc < 2; ++kc) { \
    short8 a0_ = *(const short8*)&As[wr * 32 + 0 + l15][kc * 32 + l4 * 8]; \
    short8 a1_ = *(const short8*)&As[wr * 32 + 16 + l15][kc * 32 + l4 * 8]; \
    short8 b0_ = *(const short8*)&Bs[wc * 32 + 0 + l15][kc * 32 + l4 * 8]; \
    short8 b1_ = *(const short8*)&Bs[wc * 32 + 16 + l15][kc * 32 + l4 * 8]; \
    ACC[0][0] = __builtin_amdgcn_mfma_f32_16x16x32_bf16(a0_, b0_, ACC[0][0], 0, 0, 0); \
    ACC[0][1] = __builtin_amdgcn_mfma_f32_16x16x32_bf16(a0_, b1_, ACC[0][1], 0, 0, 0); \
    ACC[1][0] = __builtin_amdgcn_mfma_f32_16x16x32_bf16(a1_, b0_, ACC[1][0], 0, 0, 0); \
    ACC[1][1] = __builtin_amdgcn_mfma_f32_16x16x32_bf16(a1_, b1_, ACC[1][1], 0, 0, 0); \
  } }

// ============================ proj (role-bucketed, gathered rows) ============================
__global__ __launch_bounds__(256) void proj_mfma(
    const u16* __restrict__ Xb, const int* __restrict__ perm,
    const int* __restrict__ blkrole,
    const u16* __restrict__ Wqt, const u16* __restrict__ Wet, const u16* __restrict__ Wct,
    const float* __restrict__ bq, const float* __restrict__ be, const float* __restrict__ bc,
    u16* __restrict__ h, u16* __restrict__ pm) {
  const int brole = blkrole[blockIdx.y];
  if (brole < 0) return;
  GEMM_PROLOG
  const int m0 = blockIdx.y * 64;
  const int n0 = blockIdx.x * 64;
  const u16* Bt = (brole == 0) ? Wqt : (brole == 1) ? Wet : Wct;
  const float* bb = (brole == 0) ? bq : (brole == 1) ? be : bc;
  const int prow = perm[m0 + srow];
  floatx4 acc[2][2] = {};
  for (int k0 = 0; k0 < KPAD; k0 += 64) {
    STAGE_A(Xb, KPAD, prow >= 0, prow, k0)
    STAGE_B(Bt, KPAD, n0 + srow, k0)
    __syncthreads();
    MFMA_STEP(acc)
    __syncthreads();
  }
  #pragma unroll
  for (int m = 0; m < 2; ++m)
    #pragma unroll
    for (int reg = 0; reg < 4; ++reg) {
      int gr = m0 + wr * 32 + m * 16 + l4 * 4 + reg;
      int pr = perm[gr];
      if (pr >= 0) {
        #pragma unroll
        for (int n = 0; n < 2; ++n) {
          int c = n0 + wc * 32 + n * 16 + l15;
          float vo = fmaxf(acc[m][n][reg] + bb[c], 0.f);
          u16 ub = f2b(vo);
          h[(size_t)pr * 256 + c] = ub;
          pm[(size_t)pr * 256 + c] = ub;
        }
      }
    }
}

// ============================ V = h @ Wall + ball ============================
__global__ __launch_bounds__(256) void vgemm_mfma(
    const u16* __restrict__ A, const u16* __restrict__ Bt,
    const float* __restrict__ bias, u16* __restrict__ C) {
  GEMM_PROLOG
  const int m0 = blockIdx.y * 64;
  const int n0 = blockIdx.x * 64;
  const int ar = m0 + srow;
  floatx4 acc[2][2] = {};
  for (int k0 = 0; k0 < 256; k0 += 64) {
    STAGE_A(A, 256, ar < NN, ar, k0)
    STAGE_B(Bt, 256, n0 + srow, k0)
    __syncthreads();
    MFMA_STEP(acc)
    __syncthreads();
  }
  #pragma unroll
  for (int m = 0; m < 2; ++m)
    #pragma unroll
    for (int reg = 0; reg < 4; ++reg) {
      int gr = m0 + wr * 32 + m * 16 + l4 * 4 + reg;
      if (gr < NN) {
        #pragma unroll
        for (int n = 0; n < 2; ++n) {
          int c = n0 + wc * 32 + n * 16 + l15;
          C[(size_t)gr * 256 + c] = f2b(acc[m][n][reg] + bias[c]);
        }
      }
    }
}

// ============================ aggregation ============================
__global__ __launch_bounds__(256) void agg_kernel(
    const int* __restrict__ csr, const int* __restrict__ rs,
    const int* __restrict__ esrc, const float* __restrict__ ew,
    const u16* __restrict__ V, u16* __restrict__ comb) {
  int n = blockIdx.x * 4 + (threadIdx.x >> 6);
  int l = threadIdx.x & 63;
  if (n >= NN) return;
  int s = rs[n], e = rs[n + 1];
  float a0 = 0.f, a1 = 0.f, a2 = 0.f, a3 = 0.f;
  for (int j = s; j < e; ++j) {
    int eid = csr[j];
    int src = esrc[eid];
    float w = ew[eid];
    ushort4 v = *(const ushort4*)&V[(size_t)src * 256 + l * 4];
    a0 = fmaf(w, b2f(v.x), a0);
    a1 = fmaf(w, b2f(v.y), a1);
    a2 = fmaf(w, b2f(v.z), a2);
    a3 = fmaf(w, b2f(v.w), a3);
  }
  ushort4 o;
  o.x = f2b(a0); o.y = f2b(a1); o.z = f2b(a2); o.w = f2b(a3);
  *(ushort4*)&comb[(size_t)n * 256 + l * 4] = o;
}

// ============================ GRU r,z gates ============================
__global__ __launch_bounds__(256) void grurz_mfma(
    const u16* __restrict__ comb, const u16* __restrict__ pmc,
    const u16* __restrict__ Wiht, const u16* __restrict__ Whht,
    const float* __restrict__ bih, const float* __restrict__ bhh,
    u16* __restrict__ R, u16* __restrict__ Z) {
  GEMM_PROLOG
  const int m0 = blockIdx.y * 64;
  const int j0 = blockIdx.x * 64;  // 0..448
  const int ar = m0 + srow;
  floatx4 acc[2][2] = {};
  #pragma unroll
  for (int p = 0; p < 2; ++p) {
    const u16* Ag = p ? pmc : comb;
    const u16* Bt = p ? Whht : Wiht;
    for (int k0 = 0; k0 < 256; k0 += 64) {
      STAGE_A(Ag, 256, ar < NN, ar, k0)
      STAGE_B(Bt, 256, j0 + srow, k0)
      __syncthreads();
      MFMA_STEP(acc)
      __syncthreads();
    }
  }
  #pragma unroll
  for (int m = 0; m < 2; ++m)
    #pragma unroll
    for (int reg = 0; reg < 4; ++reg) {
      int gr = m0 + wr * 32 + m * 16 + l4 * 4 + reg;
      if (gr < NN) {
        #pragma unroll
        for (int n = 0; n < 2; ++n) {
          int j = j0 + wc * 32 + n * 16 + l15;
          float g = sigf(acc[m][n][reg] + bih[j] + bhh[j]);
          if (j < 256) R[(size_t)gr * 256 + j] = f2b(g);
          else         Z[(size_t)gr * 256 + (j - 256)] = f2b(g);
        }
      }
    }
}

// ============================ GRU n-gate + state update ============================
__global__ __launch_bounds__(256) void grun_mfma(
    const u16* __restrict__ comb, const u16* __restrict__ pmc,
    const u16* __restrict__ Wiht, const u16* __restrict__ Whht,
    const float* __restrict__ bih, const float* __restrict__ bhh,
    const u16* __restrict__ R, const u16* __restrict__ Z,
    u16* __restrict__ pmn) {
  GEMM_PROLOG
  const int m0 = blockIdx.y * 64;
  const int n0 = blockIdx.x * 64;
  const int ar = m0 + srow;
  floatx4 ai[2][2] = {};
  floatx4 ah[2][2] = {};
  for (int k0 = 0; k0 < 256; k0 += 64) {
    STAGE_A(comb, 256, ar < NN, ar, k0)
    STAGE_B(Wiht, 256, 512 + n0 + srow, k0)
    __syncthreads();
    MFMA_STEP(ai)
    __syncthreads();
  }
  for (int k0 = 0; k0 < 256; k0 += 64) {
    STAGE_A(pmc, 256, ar < NN, ar, k0)
    STAGE_B(Whht, 256, 512 + n0 + srow, k0)
    __syncthreads();
    MFMA_STEP(ah)
    __syncthreads();
  }
  #pragma unroll
  for (int m = 0; m < 2; ++m)
    #pragma unroll
    for (int reg = 0; reg < 4; ++reg) {
      int gr = m0 + wr * 32 + m * 16 + l4 * 4 + reg;
      if (gr < NN) {
        #pragma unroll
        for (int n = 0; n < 2; ++n) {
          int c = n0 + wc * 32 + n * 16 + l15;
          float i_n = ai[m][n][reg] + bih[512 + c];
          float h_n = ah[m][n][reg] + bhh[512 + c];
          float rg = b2f(R[(size_t)gr * 256 + c]);
          float z = b2f(Z[(size_t)gr * 256 + c]);
          float po = b2f(pmc[(size_t)gr * 256 + c]);
          float nn2 = tanhf(i_n + rg * h_n);
          pmn[(size_t)gr * 256 + c] = f2b((1.f - z) * nn2 + z * po);
        }
      }
    }
}

// ============================ tmp = comb @ Wo + bo + h ============================
__global__ __launch_bounds__(256) void wo_mfma(
    const u16* __restrict__ comb, const u16* __restrict__ Wot,
    const float* __restrict__ bo, const u16* __restrict__ h,
    u16* __restrict__ tmp) {
  GEMM_PROLOG
  const int m0 = blockIdx.y * 64;
  const int n0 = blockIdx.x * 64;
  const int ar = m0 + srow;
  floatx4 acc[2][2] = {};
  for (int k0 = 0; k0 < 256; k0 += 64) {
    STAGE_A(comb, 256, ar < NN, ar, k0)
    STAGE_B(Wot, 256, n0 + srow, k0)
    __syncthreads();
    MFMA_STEP(acc)
    __syncthreads();
  }
  #pragma unroll
  for (int m = 0; m < 2; ++m)
    #pragma unroll
    for (int reg = 0; reg < 4; ++reg) {
      int gr = m0 + wr * 32 + m * 16 + l4 * 4 + reg;
      if (gr < NN) {
        #pragma unroll
        for (int n = 0; n < 2; ++n) {
          int c = n0 + wc * 32 + n * 16 + l15;
          float v = acc[m][n][reg] + bo[c] + b2f(h[(size_t)gr * 256 + c]);
          tmp[(size_t)gr * 256 + c] = f2b(v);
        }
      }
    }
}

// ============================ LayerNorm (row-wise) ============================
__global__ __launch_bounds__(256) void ln_kernel(
    const u16* __restrict__ tmp, u16* __restrict__ h,
    const float* __restrict__ lnw, const float* __restrict__ lnb) {
  int n = blockIdx.x * 4 + (threadIdx.x >> 6);
  int l = threadIdx.x & 63;
  if (n >= NN) return;
  ushort4 v = *(const ushort4*)&tmp[(size_t)n * 256 + l * 4];
  float x0 = b2f(v.x), x1 = b2f(v.y), x2 = b2f(v.z), x3 = b2f(v.w);
  float s = x0 + x1 + x2 + x3;
  #pragma unroll
  for (int off = 1; off < 64; off <<= 1) s += __shfl_xor(s, off);
  float mu = s * (1.f / 256.f);
  float d0 = x0 - mu, d1 = x1 - mu, d2 = x2 - mu, d3 = x3 - mu;
  float vs = d0 * d0 + d1 * d1 + d2 * d2 + d3 * d3;
  #pragma unroll
  for (int off = 1; off < 64; off <<= 1) vs += __shfl_xor(vs, off);
  float inv = rsqrtf(vs * (1.f / 256.f) + 1e-5f);
  int c = l * 4;
  ushort4 o;
  o.x = f2b(d0 * inv * lnw[c + 0] + lnb[c + 0]);
  o.y = f2b(d1 * inv * lnw[c + 1] + lnb[c + 1]);
  o.z = f2b(d2 * inv * lnw[c + 2] + lnb[c + 2]);
  o.w = f2b(d3 * inv * lnw[c + 3] + lnb[c + 3]);
  *(ushort4*)&h[(size_t)n * 256 + c] = o;
}

// ============================ out = h + pm (f32) ============================
__global__ void add_out(const u16* __restrict__ a, const u16* __restrict__ b,
                        float* __restrict__ o) {
  size_t i = (size_t)blockIdx.x * 256 + threadIdx.x;
  if (i < (size_t)NN * 64) {
    ushort4 x = *(const ushort4*)&a[i * 4];
    ushort4 y = *(const ushort4*)&b[i * 4];
    float4 r;
    r.x = b2f(x.x) + b2f(y.x);
    r.y = b2f(x.y) + b2f(y.y);
    r.z = b2f(x.z) + b2f(y.z);
    r.w = b2f(x.w) + b2f(y.w);
    *(float4*)&o[i * 4] = r;
  }
}

extern "C" void kernel_launch(void* const* d_in, const int* in_sizes, int n_in,
                              void* d_out, int out_size, void* d_ws, size_t ws_size,
                              hipStream_t stream) {
  const float* node_feats = (const float*)d_in[0];
  const int* role = (const int*)d_in[1];
  const int* esrc = (const int*)d_in[2];
  const int* edst = (const int*)d_in[3];
  const float* ew = (const float*)d_in[4];
  const float* Wq = (const float*)d_in[5];
  const float* bq = (const float*)d_in[6];
  const float* We = (const float*)d_in[7];
  const float* be = (const float*)d_in[8];
  const float* Wc = (const float*)d_in[9];
  const float* bc = (const float*)d_in[10];
  const float* Wv = (const float*)d_in[11];
  const float* bv = (const float*)d_in[12];
  const float* Wd = (const float*)d_in[13];
  const float* bd = (const float*)d_in[14];
  const float* Wo = (const float*)d_in[15];
  const float* bo = (const float*)d_in[16];
  const float* Wih = (const float*)d_in[17];
  const float* Whh = (const float*)d_in[18];
  const float* bih = (const float*)d_in[19];
  const float* bhh = (const float*)d_in[20];
  const float* lnw = (const float*)d_in[21];
  const float* lnb = (const float*)d_in[22];
  float* out = (float*)d_out;

  char* ws = (char*)d_ws;
  size_t off = 0;
  auto take = [&](size_t bytes) {
    char* p = ws + off;
    off = (off + bytes + 255) & ~(size_t)255;
    return p;
  };
  const size_t NC2 = (size_t)NN * 256 * 2;
  u16* Xb = (u16*)take((size_t)NN * KPAD * 2);
  u16* h = (u16*)take(NC2);
  u16* pm0 = (u16*)take(NC2);
  u16* pm1 = (u16*)take(NC2);
  u16* V = (u16*)take(NC2);   // aliased as R after agg consumes it
  u16* comb = (u16*)take(NC2);
  u16* Z = (u16*)take(NC2);
  u16* tmp = (u16*)take(NC2);
  u16* Wqt = (u16*)take((size_t)256 * KPAD * 2);
  u16* Wet = (u16*)take((size_t)256 * KPAD * 2);
  u16* Wct = (u16*)take((size_t)256 * KPAD * 2);
  u16* Wallt = (u16*)take((size_t)256 * 256 * 2);
  u16* Wot = (u16*)take((size_t)256 * 256 * 2);
  u16* Wiht = (u16*)take((size_t)768 * 256 * 2);
  u16* Whht = (u16*)take((size_t)768 * 256 * 2);
  float* ball = (float*)take(256 * 4);
  int* cnt = (int*)take((size_t)NN * 4);
  int* rs = (int*)take((size_t)(NN + 1) * 4);
  int* ncnt = (int*)take((size_t)NN * 4);
  int* csr = (int*)take((size_t)EE * 4);
  int* cnt3 = (int*)take(16);
  int* pos3 = (int*)take(16);
  int* pbase = (int*)take(16);
  int* blkrole = (int*)take((size_t)NBLK * 4);
  int* perm = (int*)take((size_t)NBLK * 64 * 4);
  u16* R = V;

  hipMemsetAsync(cnt, 0, (size_t)NN * 4, stream);
  hipMemsetAsync(ncnt, 0, (size_t)NN * 4, stream);
  hipMemsetAsync(cnt3, 0, 16, stream);
  hipMemsetAsync(pos3, 0, 16, stream);
  hipMemsetAsync(perm, 0xFF, (size_t)NBLK * 64 * 4, stream);

  count_kernel<<<(EE + 255) / 256, 256, 0, stream>>>(edst, cnt);
  scan_kernel<<<1, 1024, 0, stream>>>(cnt, rs);
  fill_kernel<<<(EE + 255) / 256, 256, 0, stream>>>(edst, rs, ncnt, csr);

  role_count<<<(NN + 255) / 256, 256, 0, stream>>>(role, cnt3);
  role_plan<<<1, 256, 0, stream>>>(cnt3, pbase, blkrole);
  role_fill<<<(NN + 255) / 256, 256, 0, stream>>>(role, pbase, pos3, perm);

  xcast_kernel<<<(int)(((size_t)NN * KPAD + 255) / 256), 256, 0, stream>>>(node_feats, Xb);
  wt3_kernel<<<dim3(256, 3), 256, 0, stream>>>(Wq, We, Wc, Wqt, Wet, Wct);
  wallt_kernel<<<256, 256, 0, stream>>>(Wv, Wd, Wallt);
  ball_kernel<<<1, 256, 0, stream>>>(bv, Wd, bd, ball);
  wot_kernel<<<256, 256, 0, stream>>>(Wo, Wot);
  castbf2_kernel<<<(2 * 768 * 256 + 255) / 256, 256, 0, stream>>>(Wih, Whh, Wiht, Whht);

  proj_mfma<<<dim3(4, NBLK), 256, 0, stream>>>(Xb, perm, blkrole, Wqt, Wet, Wct,
                                               bq, be, bc, h, pm0);

  u16* pmc = pm0;
  u16* pmn = pm1;
  const int MB = (NN + 63) / 64;  // 782
  for (int layer = 0; layer < NL; ++layer) {
    vgemm_mfma<<<dim3(4, MB), 256, 0, stream>>>(h, Wallt, ball, V);
    agg_kernel<<<(NN + 3) / 4, 256, 0, stream>>>(csr, rs, esrc, ew, V, comb);
    grurz_mfma<<<dim3(8, MB), 256, 0, stream>>>(comb, pmc, Wiht, Whht, bih, bhh, R, Z);
    grun_mfma<<<dim3(4, MB), 256, 0, stream>>>(comb, pmc, Wiht, Whht, bih, bhh, R, Z, pmn);
    wo_mfma<<<dim3(4, MB), 256, 0, stream>>>(comb, Wot, bo, h, tmp);
    ln_kernel<<<(NN + 3) / 4, 256, 0, stream>>>(tmp, h, lnw + layer * 256, lnb + layer * 256);
    u16* sw = pmc; pmc = pmn; pmn = sw;
  }

  add_out<<<(int)(((size_t)NN * 64 + 255) / 256), 256, 0, stream>>>(h, pmc, out);
}

// Round 4
// 1275.088 us; speedup vs baseline: 3.2141x; 1.2849x over previous
//
#include <hip/hip_runtime.h>
#include <math.h>

#define NN 50000
#define EE 1600000
#define IND 300
#define KPAD 320
#define NL 3
#define NBLK 785

typedef unsigned short u16;
typedef __attribute__((ext_vector_type(8))) short short8;
typedef __attribute__((ext_vector_type(4))) float floatx4;

__device__ __forceinline__ float b2f(u16 u) {
  union { unsigned i; float f; } v; v.i = ((unsigned)u) << 16; return v.f;
}
__device__ __forceinline__ u16 f2b(float f) {
  union { unsigned i; float f; } v; v.f = f;
  unsigned b = v.i; b += 0x7fffu + ((b >> 16) & 1u);
  return (u16)(b >> 16);
}
__device__ __forceinline__ float sigf(float x) { return 1.0f / (1.0f + __expf(-x)); }

// ============================ CSR build ============================
__global__ void count_kernel(const int* __restrict__ dst, int* __restrict__ cnt) {
  int e = blockIdx.x * 256 + threadIdx.x;
  if (e < EE) atomicAdd(&cnt[dst[e]], 1);
}

__global__ void scan_kernel(const int* __restrict__ cnt, int* __restrict__ rs) {
  __shared__ int wsum[16], wpre[16];
  __shared__ int carryS, totS;
  const int t = threadIdx.x;
  const int l = t & 63, wid = t >> 6;
  if (t == 0) carryS = 0;
  __syncthreads();
  for (int base = 0; base < NN; base += 1024) {
    const int carry = carryS;
    const int i = base + t;
    int v = (i < NN) ? cnt[i] : 0;
    int x = v;
    #pragma unroll
    for (int off = 1; off < 64; off <<= 1) {
      int y = __shfl_up(x, off);
      if (l >= off) x += y;
    }
    if (l == 63) wsum[wid] = x;
    __syncthreads();
    if (t < 16) {
      int s = wsum[t];
      int xx = s;
      #pragma unroll
      for (int off = 1; off < 16; off <<= 1) {
        int y = __shfl_up(xx, off);
        if (t >= off) xx += y;
      }
      wpre[t] = xx - s;
      if (t == 15) totS = xx;
    }
    __syncthreads();
    if (i < NN) rs[i] = carry + wpre[wid] + (x - v);
    __syncthreads();
    if (t == 0) carryS = carry + totS;
    __syncthreads();
  }
  if (t == 0) rs[NN] = carryS;
}

// writes flattened (src, weight) pairs in CSR slot order; all reads sequential
__global__ void fill_kernel(const int* __restrict__ dst, const int* __restrict__ rs,
                            int* __restrict__ ncnt, const int* __restrict__ esrc,
                            const float* __restrict__ ew, int2* __restrict__ srcw) {
  int e = blockIdx.x * 256 + threadIdx.x;
  if (e < EE) {
    int d = dst[e];
    int p = atomicAdd(&ncnt[d], 1);
    int2 v;
    v.x = esrc[e];
    v.y = __float_as_int(ew[e]);
    srcw[rs[d] + p] = v;
  }
}

// ============================ role bucketing (contention-free) ============================
__global__ void role_count(const int* __restrict__ role, int* __restrict__ cnt3) {
  __shared__ int lc[3];
  if (threadIdx.x < 3) lc[threadIdx.x] = 0;
  __syncthreads();
  int i = blockIdx.x * 256 + threadIdx.x;
  if (i < NN) atomicAdd(&lc[role[i]], 1);
  __syncthreads();
  if (threadIdx.x < 3) atomicAdd(&cnt3[threadIdx.x], lc[threadIdx.x]);
}

__global__ void role_plan(const int* __restrict__ cnt3, int* __restrict__ pbase,
                          int* __restrict__ blkrole) {
  __shared__ int pb[4];
  if (threadIdx.x == 0) {
    pb[0] = 0;
    for (int b = 0; b < 3; ++b) pb[b + 1] = pb[b] + (((cnt3[b] + 63) >> 6) << 6);
    for (int b = 0; b < 4; ++b) pbase[b] = pb[b];
  }
  __syncthreads();
  for (int blk = threadIdx.x; blk < NBLK; blk += 256) {
    int m0 = blk * 64;
    int r = -1;
    for (int b = 0; b < 3; ++b)
      if (m0 >= pb[b] && m0 < pb[b + 1]) r = b;
    blkrole[blk] = r;
  }
}

__global__ void role_fill(const int* __restrict__ role, const int* __restrict__ pbase,
                          int* __restrict__ pos3, int* __restrict__ perm) {
  __shared__ int lcnt[3], lbase[3];
  int i = blockIdx.x * 256 + threadIdx.x;
  if (threadIdx.x < 3) lcnt[threadIdx.x] = 0;
  __syncthreads();
  int r = 0, lr = 0;
  bool valid = (i < NN);
  if (valid) {
    r = role[i];
    lr = atomicAdd(&lcnt[r], 1);
  }
  __syncthreads();
  if (threadIdx.x < 3) lbase[threadIdx.x] = atomicAdd(&pos3[threadIdx.x], lcnt[threadIdx.x]);
  __syncthreads();
  if (valid) perm[pbase[r] + lbase[r] + lr] = i;
}

// ============================ weight prep ============================
__global__ void xcast_kernel(const float* __restrict__ X, u16* __restrict__ Xb) {
  size_t i = (size_t)blockIdx.x * 256 + threadIdx.x;
  if (i >= (size_t)NN * KPAD) return;
  int r = (int)(i / KPAD), k = (int)(i % KPAD);
  Xb[i] = (k < IND) ? f2b(X[(size_t)r * IND + k]) : (u16)0;
}

__global__ void wt3_kernel(const float* __restrict__ Wq, const float* __restrict__ We,
                           const float* __restrict__ Wc, u16* __restrict__ Wqt,
                           u16* __restrict__ Wet, u16* __restrict__ Wct) {
  int n = blockIdx.x;
  int which = blockIdx.y;
  const float* W = (which == 0) ? Wq : (which == 1) ? We : Wc;
  u16* Wt = (which == 0) ? Wqt : (which == 1) ? Wet : Wct;
  for (int k = threadIdx.x; k < KPAD; k += 256)
    Wt[(size_t)n * KPAD + k] = (k < IND) ? f2b(W[(size_t)k * 256 + n]) : (u16)0;
}

__global__ void wallt_kernel(const float* __restrict__ Wv, const float* __restrict__ Wd,
                             u16* __restrict__ Wallt) {
  int i = blockIdx.x;
  int c = threadIdx.x;
  int hd = c >> 6, j = c & 63;
  const float* wv = &Wv[hd * (256 * 64) + i * 64];
  float s = 0.f;
  #pragma unroll
  for (int m = 0; m < 64; ++m) s = fmaf(wv[m], Wd[m * 64 + j], s);
  Wallt[(size_t)c * 256 + i] = f2b(s);
}

__global__ void ball_kernel(const float* __restrict__ bv, const float* __restrict__ Wd,
                            const float* __restrict__ bd, float* __restrict__ ball) {
  int c = threadIdx.x;
  int hd = c >> 6, j = c & 63;
  float s = bd[j];
  #pragma unroll
  for (int m = 0; m < 64; ++m) s = fmaf(bv[hd * 64 + m], Wd[m * 64 + j], s);
  ball[c] = s;
}

__global__ void wot_kernel(const float* __restrict__ Wo, u16* __restrict__ Wot) {
  int n = blockIdx.x;
  int k = threadIdx.x;
  Wot[(size_t)n * 256 + k] = f2b(Wo[(size_t)k * 256 + n]);
}

__global__ void castbf2_kernel(const float* __restrict__ s0, const float* __restrict__ s1,
                               u16* __restrict__ d0, u16* __restrict__ d1) {
  int i = blockIdx.x * 256 + threadIdx.x;
  const int n = 768 * 256;
  if (i < n) d0[i] = f2b(s0[i]);
  else if (i < 2 * n) d1[i - n] = f2b(s1[i - n]);
}

// ============================ 64-tile MFMA (proj only) ============================
#define GEMM_PROLOG \
  __shared__ __align__(16) u16 As[64][72]; \
  __shared__ __align__(16) u16 Bs[64][72]; \
  const int t = threadIdx.x; \
  const int lane = t & 63; \
  const int wv_ = t >> 6; \
  const int wr = wv_ >> 1, wc = wv_ & 1; \
  const int l15 = lane & 15, l4 = lane >> 4; \
  const int srow = t >> 2; \
  const int scol = (t & 3) << 4;

#define STAGE_A(AG, ASTRIDE, VALID, ROWIDX, K0) { \
  int4 v0 = {0, 0, 0, 0}, v1 = {0, 0, 0, 0}; \
  if (VALID) { \
    const int4* p_ = (const int4*)&(AG)[(size_t)(ROWIDX) * (ASTRIDE) + (K0) + scol]; \
    v0 = p_[0]; v1 = p_[1]; \
  } \
  *(int4*)&As[srow][scol] = v0; \
  *(int4*)&As[srow][scol + 8] = v1; }

#define STAGE_B(BG, BSTRIDE, ROWIDX, K0) { \
  const int4* p_ = (const int4*)&(BG)[(size_t)(ROWIDX) * (BSTRIDE) + (K0) + scol]; \
  *(int4*)&Bs[srow][scol] = p_[0]; \
  *(int4*)&Bs[srow][scol + 8] = p_[1]; }

#define MFMA_STEP(ACC) { \
  _Pragma("unroll") \
  for (int kc = 0; kc < 2; ++kc) { \
    short8 a0_ = *(const short8*)&As[wr * 32 + 0 + l15][kc * 32 + l4 * 8]; \
    short8 a1_ = *(const short8*)&As[wr * 32 + 16 + l15][kc * 32 + l4 * 8]; \
    short8 b0_ = *(const short8*)&Bs[wc * 32 + 0 + l15][kc * 32 + l4 * 8]; \
    short8 b1_ = *(const short8*)&Bs[wc * 32 + 16 + l15][kc * 32 + l4 * 8]; \
    ACC[0][0] = __builtin_amdgcn_mfma_f32_16x16x32_bf16(a0_, b0_, ACC[0][0], 0, 0, 0); \
    ACC[0][1] = __builtin_amdgcn_mfma_f32_16x16x32_bf16(a0_, b1_, ACC[0][1], 0, 0, 0); \
    ACC[1][0] = __builtin_amdgcn_mfma_f32_16x16x32_bf16(a1_, b0_, ACC[1][0], 0, 0, 0); \
    ACC[1][1] = __builtin_amdgcn_mfma_f32_16x16x32_bf16(a1_, b1_, ACC[1][1], 0, 0, 0); \
  } }

// ============================ 128-tile MFMA (main GEMMs) ============================
#define GEMM128_PROLOG \
  __shared__ __align__(16) u16 As[128][72]; \
  __shared__ __align__(16) u16 Bs[128][72]; \
  const int t = threadIdx.x; \
  const int lane = t & 63; \
  const int wv_ = t >> 6; \
  const int qr = (wv_ >> 1) * 64, qc = (wv_ & 1) * 64; \
  const int l15 = lane & 15, l4 = lane >> 4; \
  const int srow = t >> 1; \
  const int scol = (t & 1) * 32;

#define STAGE128_A(AG, ASTRIDE, VALID, ROWIDX, K0) { \
  int4 v0 = {0,0,0,0}, v1 = {0,0,0,0}, v2 = {0,0,0,0}, v3 = {0,0,0,0}; \
  if (VALID) { \
    const int4* p_ = (const int4*)&(AG)[(size_t)(ROWIDX) * (ASTRIDE) + (K0) + scol]; \
    v0 = p_[0]; v1 = p_[1]; v2 = p_[2]; v3 = p_[3]; \
  } \
  *(int4*)&As[srow][scol] = v0; *(int4*)&As[srow][scol + 8] = v1; \
  *(int4*)&As[srow][scol + 16] = v2; *(int4*)&As[srow][scol + 24] = v3; }

#define STAGE128_B(BG, BSTRIDE, ROWIDX, K0) { \
  const int4* p_ = (const int4*)&(BG)[(size_t)(ROWIDX) * (BSTRIDE) + (K0) + scol]; \
  *(int4*)&Bs[srow][scol] = p_[0]; *(int4*)&Bs[srow][scol + 8] = p_[1]; \
  *(int4*)&Bs[srow][scol + 16] = p_[2]; *(int4*)&Bs[srow][scol + 24] = p_[3]; }

#define MFMA128_STEP(ACC) { \
  _Pragma("unroll") \
  for (int kc = 0; kc < 2; ++kc) { \
    short8 af_[4], bf_[4]; \
    _Pragma("unroll") \
    for (int m = 0; m < 4; ++m) af_[m] = *(const short8*)&As[qr + m * 16 + l15][kc * 32 + l4 * 8]; \
    _Pragma("unroll") \
    for (int n = 0; n < 4; ++n) bf_[n] = *(const short8*)&Bs[qc + n * 16 + l15][kc * 32 + l4 * 8]; \
    _Pragma("unroll") \
    for (int m = 0; m < 4; ++m) \
      _Pragma("unroll") \
      for (int n = 0; n < 4; ++n) \
        ACC[m][n] = __builtin_amdgcn_mfma_f32_16x16x32_bf16(af_[m], bf_[n], ACC[m][n], 0, 0, 0); \
  } }

// ============================ proj (role-bucketed, 64-tile) ============================
__global__ __launch_bounds__(256) void proj_mfma(
    const u16* __restrict__ Xb, const int* __restrict__ perm,
    const int* __restrict__ blkrole,
    const u16* __restrict__ Wqt, const u16* __restrict__ Wet, const u16* __restrict__ Wct,
    const float* __restrict__ bq, const float* __restrict__ be, const float* __restrict__ bc,
    u16* __restrict__ h, u16* __restrict__ pm) {
  const int brole = blkrole[blockIdx.y];
  if (brole < 0) return;
  GEMM_PROLOG
  const int m0 = blockIdx.y * 64;
  const int n0 = blockIdx.x * 64;
  const u16* Bt = (brole == 0) ? Wqt : (brole == 1) ? Wet : Wct;
  const float* bb = (brole == 0) ? bq : (brole == 1) ? be : bc;
  const int prow = perm[m0 + srow];
  floatx4 acc[2][2] = {};
  for (int k0 = 0; k0 < KPAD; k0 += 64) {
    STAGE_A(Xb, KPAD, prow >= 0, prow, k0)
    STAGE_B(Bt, KPAD, n0 + srow, k0)
    __syncthreads();
    MFMA_STEP(acc)
    __syncthreads();
  }
  #pragma unroll
  for (int m = 0; m < 2; ++m)
    #pragma unroll
    for (int reg = 0; reg < 4; ++reg) {
      int gr = m0 + wr * 32 + m * 16 + l4 * 4 + reg;
      int pr = perm[gr];
      if (pr >= 0) {
        #pragma unroll
        for (int n = 0; n < 2; ++n) {
          int c = n0 + wc * 32 + n * 16 + l15;
          float vo = fmaxf(acc[m][n][reg] + bb[c], 0.f);
          u16 ub = f2b(vo);
          h[(size_t)pr * 256 + c] = ub;
          pm[(size_t)pr * 256 + c] = ub;
        }
      }
    }
}

// ============================ V = h @ Wall + ball (128-tile) ============================
__global__ __launch_bounds__(256) void vgemm_mfma(
    const u16* __restrict__ A, const u16* __restrict__ Bt,
    const float* __restrict__ bias, u16* __restrict__ C) {
  GEMM128_PROLOG
  const int m0 = blockIdx.y * 128;
  const int n0 = blockIdx.x * 128;
  const int ar = m0 + srow;
  floatx4 acc[4][4] = {};
  for (int k0 = 0; k0 < 256; k0 += 64) {
    STAGE128_A(A, 256, ar < NN, ar, k0)
    STAGE128_B(Bt, 256, n0 + srow, k0)
    __syncthreads();
    MFMA128_STEP(acc)
    __syncthreads();
  }
  #pragma unroll
  for (int m = 0; m < 4; ++m)
    #pragma unroll
    for (int reg = 0; reg < 4; ++reg) {
      int gr = m0 + qr + m * 16 + l4 * 4 + reg;
      if (gr < NN) {
        #pragma unroll
        for (int n = 0; n < 4; ++n) {
          int c = n0 + qc + n * 16 + l15;
          C[(size_t)gr * 256 + c] = f2b(acc[m][n][reg] + bias[c]);
        }
      }
    }
}

// ============================ aggregation (flattened srcw, shfl-broadcast) ============================
__global__ __launch_bounds__(256) void agg_kernel(
    const int2* __restrict__ srcw, const int* __restrict__ rs,
    const u16* __restrict__ V, u16* __restrict__ comb) {
  int n = blockIdx.x * 4 + (threadIdx.x >> 6);
  int l = threadIdx.x & 63;
  if (n >= NN) return;
  int s = rs[n], e = rs[n + 1];
  float a0 = 0.f, a1 = 0.f, a2 = 0.f, a3 = 0.f;
  for (int base = s; base < e; base += 64) {
    int2 p = {0, 0};
    if (base + l < e) p = srcw[base + l];
    int cnt = min(64, e - base);
    for (int j = 0; j < cnt; ++j) {
      int src = __shfl(p.x, j);
      float w = __int_as_float(__shfl(p.y, j));
      ushort4 v = *(const ushort4*)&V[(size_t)src * 256 + l * 4];
      a0 = fmaf(w, b2f(v.x), a0);
      a1 = fmaf(w, b2f(v.y), a1);
      a2 = fmaf(w, b2f(v.z), a2);
      a3 = fmaf(w, b2f(v.w), a3);
    }
  }
  ushort4 o;
  o.x = f2b(a0); o.y = f2b(a1); o.z = f2b(a2); o.w = f2b(a3);
  *(ushort4*)&comb[(size_t)n * 256 + l * 4] = o;
}

// ============================ GRU r,z gates (128-tile) ============================
__global__ __launch_bounds__(256) void grurz_mfma(
    const u16* __restrict__ comb, const u16* __restrict__ pmc,
    const u16* __restrict__ Wiht, const u16* __restrict__ Whht,
    const float* __restrict__ bih, const float* __restrict__ bhh,
    u16* __restrict__ R, u16* __restrict__ Z) {
  GEMM128_PROLOG
  const int m0 = blockIdx.y * 128;
  const int j0 = blockIdx.x * 128;  // 0..384
  const int ar = m0 + srow;
  floatx4 acc[4][4] = {};
  #pragma unroll
  for (int p = 0; p < 2; ++p) {
    const u16* Ag = p ? pmc : comb;
    const u16* Bt = p ? Whht : Wiht;
    for (int k0 = 0; k0 < 256; k0 += 64) {
      STAGE128_A(Ag, 256, ar < NN, ar, k0)
      STAGE128_B(Bt, 256, j0 + srow, k0)
      __syncthreads();
      MFMA128_STEP(acc)
      __syncthreads();
    }
  }
  #pragma unroll
  for (int m = 0; m < 4; ++m)
    #pragma unroll
    for (int reg = 0; reg < 4; ++reg) {
      int gr = m0 + qr + m * 16 + l4 * 4 + reg;
      if (gr < NN) {
        #pragma unroll
        for (int n = 0; n < 4; ++n) {
          int j = j0 + qc + n * 16 + l15;
          float g = sigf(acc[m][n][reg] + bih[j] + bhh[j]);
          if (j < 256) R[(size_t)gr * 256 + j] = f2b(g);
          else         Z[(size_t)gr * 256 + (j - 256)] = f2b(g);
        }
      }
    }
}

// ============================ GRU n-gate + state update (128-tile) ============================
__global__ __launch_bounds__(256) void grun_mfma(
    const u16* __restrict__ comb, const u16* __restrict__ pmc,
    const u16* __restrict__ Wiht, const u16* __restrict__ Whht,
    const float* __restrict__ bih, const float* __restrict__ bhh,
    const u16* __restrict__ R, const u16* __restrict__ Z,
    u16* __restrict__ pmn) {
  GEMM128_PROLOG
  const int m0 = blockIdx.y * 128;
  const int n0 = blockIdx.x * 128;
  const int ar = m0 + srow;
  floatx4 ai[4][4] = {};
  floatx4 ah[4][4] = {};
  for (int k0 = 0; k0 < 256; k0 += 64) {
    STAGE128_A(comb, 256, ar < NN, ar, k0)
    STAGE128_B(Wiht, 256, 512 + n0 + srow, k0)
    __syncthreads();
    MFMA128_STEP(ai)
    __syncthreads();
  }
  for (int k0 = 0; k0 < 256; k0 += 64) {
    STAGE128_A(pmc, 256, ar < NN, ar, k0)
    STAGE128_B(Whht, 256, 512 + n0 + srow, k0)
    __syncthreads();
    MFMA128_STEP(ah)
    __syncthreads();
  }
  #pragma unroll
  for (int m = 0; m < 4; ++m)
    #pragma unroll
    for (int reg = 0; reg < 4; ++reg) {
      int gr = m0 + qr + m * 16 + l4 * 4 + reg;
      if (gr < NN) {
        #pragma unroll
        for (int n = 0; n < 4; ++n) {
          int c = n0 + qc + n * 16 + l15;
          float i_n = ai[m][n][reg] + bih[512 + c];
          float h_n = ah[m][n][reg] + bhh[512 + c];
          float rg = b2f(R[(size_t)gr * 256 + c]);
          float z = b2f(Z[(size_t)gr * 256 + c]);
          float po = b2f(pmc[(size_t)gr * 256 + c]);
          float nn2 = tanhf(i_n + rg * h_n);
          pmn[(size_t)gr * 256 + c] = f2b((1.f - z) * nn2 + z * po);
        }
      }
    }
}

// ============================ tmp = comb @ Wo + bo + h (128-tile) ============================
__global__ __launch_bounds__(256) void wo_mfma(
    const u16* __restrict__ comb, const u16* __restrict__ Wot,
    const float* __restrict__ bo, const u16* __restrict__ h,
    u16* __restrict__ tmp) {
  GEMM128_PROLOG
  const int m0 = blockIdx.y * 128;
  const int n0 = blockIdx.x * 128;
  const int ar = m0 + srow;
  floatx4 acc[4][4] = {};
  for (int k0 = 0; k0 < 256; k0 += 64) {
    STAGE128_A(comb, 256, ar < NN, ar, k0)
    STAGE128_B(Wot, 256, n0 + srow, k0)
    __syncthreads();
    MFMA128_STEP(acc)
    __syncthreads();
  }
  #pragma unroll
  for (int m = 0; m < 4; ++m)
    #pragma unroll
    for (int reg = 0; reg < 4; ++reg) {
      int gr = m0 + qr + m * 16 + l4 * 4 + reg;
      if (gr < NN) {
        #pragma unroll
        for (int n = 0; n < 4; ++n) {
          int c = n0 + qc + n * 16 + l15;
          float v = acc[m][n][reg] + bo[c] + b2f(h[(size_t)gr * 256 + c]);
          tmp[(size_t)gr * 256 + c] = f2b(v);
        }
      }
    }
}

// ============================ LayerNorm (row-wise) ============================
__global__ __launch_bounds__(256) void ln_kernel(
    const u16* __restrict__ tmp, u16* __restrict__ h,
    const float* __restrict__ lnw, const float* __restrict__ lnb) {
  int n = blockIdx.x * 4 + (threadIdx.x >> 6);
  int l = threadIdx.x & 63;
  if (n >= NN) return;
  ushort4 v = *(const ushort4*)&tmp[(size_t)n * 256 + l * 4];
  float x0 = b2f(v.x), x1 = b2f(v.y), x2 = b2f(v.z), x3 = b2f(v.w);
  float s = x0 + x1 + x2 + x3;
  #pragma unroll
  for (int off = 1; off < 64; off <<= 1) s += __shfl_xor(s, off);
  float mu = s * (1.f / 256.f);
  float d0 = x0 - mu, d1 = x1 - mu, d2 = x2 - mu, d3 = x3 - mu;
  float vs = d0 * d0 + d1 * d1 + d2 * d2 + d3 * d3;
  #pragma unroll
  for (int off = 1; off < 64; off <<= 1) vs += __shfl_xor(vs, off);
  float inv = rsqrtf(vs * (1.f / 256.f) + 1e-5f);
  int c = l * 4;
  ushort4 o;
  o.x = f2b(d0 * inv * lnw[c + 0] + lnb[c + 0]);
  o.y = f2b(d1 * inv * lnw[c + 1] + lnb[c + 1]);
  o.z = f2b(d2 * inv * lnw[c + 2] + lnb[c + 2]);
  o.w = f2b(d3 * inv * lnw[c + 3] + lnb[c + 3]);
  *(ushort4*)&h[(size_t)n * 256 + c] = o;
}

// ============================ out = h + pm (f32) ============================
__global__ void add_out(const u16* __restrict__ a, const u16* __restrict__ b,
                        float* __restrict__ o) {
  size_t i = (size_t)blockIdx.x * 256 + threadIdx.x;
  if (i < (size_t)NN * 64) {
    ushort4 x = *(const ushort4*)&a[i * 4];
    ushort4 y = *(const ushort4*)&b[i * 4];
    float4 r;
    r.x = b2f(x.x) + b2f(y.x);
    r.y = b2f(x.y) + b2f(y.y);
    r.z = b2f(x.z) + b2f(y.z);
    r.w = b2f(x.w) + b2f(y.w);
    *(float4*)&o[i * 4] = r;
  }
}

extern "C" void kernel_launch(void* const* d_in, const int* in_sizes, int n_in,
                              void* d_out, int out_size, void* d_ws, size_t ws_size,
                              hipStream_t stream) {
  const float* node_feats = (const float*)d_in[0];
  const int* role = (const int*)d_in[1];
  const int* esrc = (const int*)d_in[2];
  const int* edst = (const int*)d_in[3];
  const float* ew = (const float*)d_in[4];
  const float* Wq = (const float*)d_in[5];
  const float* bq = (const float*)d_in[6];
  const float* We = (const float*)d_in[7];
  const float* be = (const float*)d_in[8];
  const float* Wc = (const float*)d_in[9];
  const float* bc = (const float*)d_in[10];
  const float* Wv = (const float*)d_in[11];
  const float* bv = (const float*)d_in[12];
  const float* Wd = (const float*)d_in[13];
  const float* bd = (const float*)d_in[14];
  const float* Wo = (const float*)d_in[15];
  const float* bo = (const float*)d_in[16];
  const float* Wih = (const float*)d_in[17];
  const float* Whh = (const float*)d_in[18];
  const float* bih = (const float*)d_in[19];
  const float* bhh = (const float*)d_in[20];
  const float* lnw = (const float*)d_in[21];
  const float* lnb = (const float*)d_in[22];
  float* out = (float*)d_out;

  char* ws = (char*)d_ws;
  size_t off = 0;
  auto take = [&](size_t bytes) {
    char* p = ws + off;
    off = (off + bytes + 511) & ~(size_t)511;
    return p;
  };
  const size_t NC2 = (size_t)NN * 256 * 2;
  u16* Xb = (u16*)take((size_t)NN * KPAD * 2);
  u16* h = (u16*)take(NC2);
  u16* pm0 = (u16*)take(NC2);
  u16* pm1 = (u16*)take(NC2);
  u16* V = (u16*)take(NC2);   // aliased as R after agg consumes it
  u16* comb = (u16*)take(NC2);
  u16* Z = (u16*)take(NC2);
  u16* tmp = (u16*)take(NC2);
  u16* Wqt = (u16*)take((size_t)256 * KPAD * 2);
  u16* Wet = (u16*)take((size_t)256 * KPAD * 2);
  u16* Wct = (u16*)take((size_t)256 * KPAD * 2);
  u16* Wallt = (u16*)take((size_t)256 * 256 * 2);
  u16* Wot = (u16*)take((size_t)256 * 256 * 2);
  u16* Wiht = (u16*)take((size_t)768 * 256 * 2);
  u16* Whht = (u16*)take((size_t)768 * 256 * 2);
  float* ball = (float*)take(256 * 4);
  int* cnt = (int*)take((size_t)NN * 4);
  int* rs = (int*)take((size_t)(NN + 1) * 4);
  int* ncnt = (int*)take((size_t)NN * 4);
  int2* srcw = (int2*)take((size_t)EE * 8);
  int* cnt3 = (int*)take(16);
  int* pos3 = (int*)take(16);
  int* pbase = (int*)take(16);
  int* blkrole = (int*)take((size_t)NBLK * 4);
  int* perm = (int*)take((size_t)NBLK * 64 * 4);
  u16* R = V;

  hipMemsetAsync(cnt, 0, (size_t)NN * 4, stream);
  hipMemsetAsync(ncnt, 0, (size_t)NN * 4, stream);
  hipMemsetAsync(cnt3, 0, 16, stream);
  hipMemsetAsync(pos3, 0, 16, stream);
  hipMemsetAsync(perm, 0xFF, (size_t)NBLK * 64 * 4, stream);

  count_kernel<<<(EE + 255) / 256, 256, 0, stream>>>(edst, cnt);
  scan_kernel<<<1, 1024, 0, stream>>>(cnt, rs);
  fill_kernel<<<(EE + 255) / 256, 256, 0, stream>>>(edst, rs, ncnt, esrc, ew, srcw);

  role_count<<<(NN + 255) / 256, 256, 0, stream>>>(role, cnt3);
  role_plan<<<1, 256, 0, stream>>>(cnt3, pbase, blkrole);
  role_fill<<<(NN + 255) / 256, 256, 0, stream>>>(role, pbase, pos3, perm);

  xcast_kernel<<<(int)(((size_t)NN * KPAD + 255) / 256), 256, 0, stream>>>(node_feats, Xb);
  wt3_kernel<<<dim3(256, 3), 256, 0, stream>>>(Wq, We, Wc, Wqt, Wet, Wct);
  wallt_kernel<<<256, 256, 0, stream>>>(Wv, Wd, Wallt);
  ball_kernel<<<1, 256, 0, stream>>>(bv, Wd, bd, ball);
  wot_kernel<<<256, 256, 0, stream>>>(Wo, Wot);
  castbf2_kernel<<<(2 * 768 * 256 + 255) / 256, 256, 0, stream>>>(Wih, Whh, Wiht, Whht);

  proj_mfma<<<dim3(4, NBLK), 256, 0, stream>>>(Xb, perm, blkrole, Wqt, Wet, Wct,
                                               bq, be, bc, h, pm0);

  u16* pmc = pm0;
  u16* pmn = pm1;
  const int MB128 = (NN + 127) / 128;  // 391
  for (int layer = 0; layer < NL; ++layer) {
    vgemm_mfma<<<dim3(2, MB128), 256, 0, stream>>>(h, Wallt, ball, V);
    agg_kernel<<<(NN + 3) / 4, 256, 0, stream>>>(srcw, rs, V, comb);
    grurz_mfma<<<dim3(4, MB128), 256, 0, stream>>>(comb, pmc, Wiht, Whht, bih, bhh, R, Z);
    grun_mfma<<<dim3(2, MB128), 256, 0, stream>>>(comb, pmc, Wiht, Whht, bih, bhh, R, Z, pmn);
    wo_mfma<<<dim3(2, MB128), 256, 0, stream>>>(comb, Wot, bo, h, tmp);
    ln_kernel<<<(NN + 3) / 4, 256, 0, stream>>>(tmp, h, lnw + layer * 256, lnb + layer * 256);
    u16* sw = pmc; pmc = pmn; pmn = sw;
  }

  add_out<<<(int)(((size_t)NN * 64 + 255) / 256), 256, 0, stream>>>(h, pmc, out);
}

// Round 5
// 1190.346 us; speedup vs baseline: 3.4429x; 1.0712x over previous
//
#include <hip/hip_runtime.h>
#include <math.h>

#define NN 50000
#define EE 1600000
#define IND 300
#define KPAD 320
#define NL 3
#define NBLK 785

typedef unsigned short u16;
typedef __attribute__((ext_vector_type(8))) short short8;
typedef __attribute__((ext_vector_type(4))) float floatx4;

__device__ __forceinline__ float b2f(u16 u) {
  union { unsigned i; float f; } v; v.i = ((unsigned)u) << 16; return v.f;
}
__device__ __forceinline__ u16 f2b(float f) {
  union { unsigned i; float f; } v; v.f = f;
  unsigned b = v.i; b += 0x7fffu + ((b >> 16) & 1u);
  return (u16)(b >> 16);
}
__device__ __forceinline__ float sigf(float x) { return 1.0f / (1.0f + __expf(-x)); }

// ============================ CSR build ============================
__global__ void count_kernel(const int* __restrict__ dst, int* __restrict__ cnt) {
  int e = blockIdx.x * 256 + threadIdx.x;
  if (e < EE) atomicAdd(&cnt[dst[e]], 1);
}

// ---- multi-block exclusive scan (3 kernels) ----
// scan1: per-block (2048 elems) local exclusive scan + block sums
__global__ __launch_bounds__(256) void scan1_kernel(const int* __restrict__ cnt,
                                                    int* __restrict__ rs,
                                                    int* __restrict__ bsum) {
  __shared__ int ws[4];
  const int t = threadIdx.x, l = t & 63, w = t >> 6;
  const int base = blockIdx.x * 2048 + t * 8;
  int v[8];
  int tot = 0;
  #pragma unroll
  for (int k = 0; k < 8; ++k) {
    int i = base + k;
    v[k] = (i < NN) ? cnt[i] : 0;
    tot += v[k];
  }
  int x = tot;
  #pragma unroll
  for (int off = 1; off < 64; off <<= 1) {
    int y = __shfl_up(x, off);
    if (l >= off) x += y;
  }
  if (l == 63) ws[w] = x;
  __syncthreads();
  int wpre = 0;
  for (int q = 0; q < w; ++q) wpre += ws[q];
  int run = wpre + (x - tot);
  #pragma unroll
  for (int k = 0; k < 8; ++k) {
    int i = base + k;
    if (i < NN) rs[i] = run;
    run += v[k];
  }
  if (t == 255) bsum[blockIdx.x] = wpre + x;
}

// scan2: exclusive scan of block sums (nb <= 64), bsum[nb] = total
__global__ void scan2_kernel(int* __restrict__ bsum, int nb) {
  int l = threadIdx.x;
  int v = (l < nb) ? bsum[l] : 0;
  int x = v;
  #pragma unroll
  for (int off = 1; off < 64; off <<= 1) {
    int y = __shfl_up(x, off);
    if (l >= off) x += y;
  }
  if (l < nb) bsum[l] = x - v;
  if (l == 63) bsum[nb] = x;
}

// scan3: add block prefix
__global__ void scan3_kernel(const int* __restrict__ bsum, int* __restrict__ rs, int nb) {
  int i = blockIdx.x * 256 + threadIdx.x;
  if (i < NN) rs[i] += bsum[i >> 11];
  if (i == 0) rs[NN] = bsum[nb];
}

// writes flattened (src, weight) pairs in CSR slot order; all reads sequential
__global__ void fill_kernel(const int* __restrict__ dst, const int* __restrict__ rs,
                            int* __restrict__ ncnt, const int* __restrict__ esrc,
                            const float* __restrict__ ew, int2* __restrict__ srcw) {
  int e = blockIdx.x * 256 + threadIdx.x;
  if (e < EE) {
    int d = dst[e];
    int p = atomicAdd(&ncnt[d], 1);
    int2 v;
    v.x = esrc[e];
    v.y = __float_as_int(ew[e]);
    srcw[rs[d] + p] = v;
  }
}

// ============================ role bucketing (contention-free) ============================
__global__ void role_count(const int* __restrict__ role, int* __restrict__ cnt3) {
  __shared__ int lc[3];
  if (threadIdx.x < 3) lc[threadIdx.x] = 0;
  __syncthreads();
  int i = blockIdx.x * 256 + threadIdx.x;
  if (i < NN) atomicAdd(&lc[role[i]], 1);
  __syncthreads();
  if (threadIdx.x < 3) atomicAdd(&cnt3[threadIdx.x], lc[threadIdx.x]);
}

__global__ void role_plan(const int* __restrict__ cnt3, int* __restrict__ pbase,
                          int* __restrict__ blkrole) {
  __shared__ int pb[4];
  if (threadIdx.x == 0) {
    pb[0] = 0;
    for (int b = 0; b < 3; ++b) pb[b + 1] = pb[b] + (((cnt3[b] + 63) >> 6) << 6);
    for (int b = 0; b < 4; ++b) pbase[b] = pb[b];
  }
  __syncthreads();
  for (int blk = threadIdx.x; blk < NBLK; blk += 256) {
    int m0 = blk * 64;
    int r = -1;
    for (int b = 0; b < 3; ++b)
      if (m0 >= pb[b] && m0 < pb[b + 1]) r = b;
    blkrole[blk] = r;
  }
}

__global__ void role_fill(const int* __restrict__ role, const int* __restrict__ pbase,
                          int* __restrict__ pos3, int* __restrict__ perm) {
  __shared__ int lcnt[3], lbase[3];
  int i = blockIdx.x * 256 + threadIdx.x;
  if (threadIdx.x < 3) lcnt[threadIdx.x] = 0;
  __syncthreads();
  int r = 0, lr = 0;
  bool valid = (i < NN);
  if (valid) {
    r = role[i];
    lr = atomicAdd(&lcnt[r], 1);
  }
  __syncthreads();
  if (threadIdx.x < 3) lbase[threadIdx.x] = atomicAdd(&pos3[threadIdx.x], lcnt[threadIdx.x]);
  __syncthreads();
  if (valid) perm[pbase[r] + lbase[r] + lr] = i;
}

// ============================ weight prep ============================
__global__ void xcast_kernel(const float* __restrict__ X, u16* __restrict__ Xb) {
  size_t i = (size_t)blockIdx.x * 256 + threadIdx.x;
  if (i >= (size_t)NN * KPAD) return;
  int r = (int)(i / KPAD), k = (int)(i % KPAD);
  Xb[i] = (k < IND) ? f2b(X[(size_t)r * IND + k]) : (u16)0;
}

__global__ void wt3_kernel(const float* __restrict__ Wq, const float* __restrict__ We,
                           const float* __restrict__ Wc, u16* __restrict__ Wqt,
                           u16* __restrict__ Wet, u16* __restrict__ Wct) {
  int n = blockIdx.x;
  int which = blockIdx.y;
  const float* W = (which == 0) ? Wq : (which == 1) ? We : Wc;
  u16* Wt = (which == 0) ? Wqt : (which == 1) ? Wet : Wct;
  for (int k = threadIdx.x; k < KPAD; k += 256)
    Wt[(size_t)n * KPAD + k] = (k < IND) ? f2b(W[(size_t)k * 256 + n]) : (u16)0;
}

__global__ void wallt_kernel(const float* __restrict__ Wv, const float* __restrict__ Wd,
                             u16* __restrict__ Wallt) {
  int i = blockIdx.x;
  int c = threadIdx.x;
  int hd = c >> 6, j = c & 63;
  const float* wv = &Wv[hd * (256 * 64) + i * 64];
  float s = 0.f;
  #pragma unroll
  for (int m = 0; m < 64; ++m) s = fmaf(wv[m], Wd[m * 64 + j], s);
  Wallt[(size_t)c * 256 + i] = f2b(s);
}

__global__ void ball_kernel(const float* __restrict__ bv, const float* __restrict__ Wd,
                            const float* __restrict__ bd, float* __restrict__ ball) {
  int c = threadIdx.x;
  int hd = c >> 6, j = c & 63;
  float s = bd[j];
  #pragma unroll
  for (int m = 0; m < 64; ++m) s = fmaf(bv[hd * 64 + m], Wd[m * 64 + j], s);
  ball[c] = s;
}

__global__ void wot_kernel(const float* __restrict__ Wo, u16* __restrict__ Wot) {
  int n = blockIdx.x;
  int k = threadIdx.x;
  Wot[(size_t)n * 256 + k] = f2b(Wo[(size_t)k * 256 + n]);
}

__global__ void castbf2_kernel(const float* __restrict__ s0, const float* __restrict__ s1,
                               u16* __restrict__ d0, u16* __restrict__ d1) {
  int i = blockIdx.x * 256 + threadIdx.x;
  const int n = 768 * 256;
  if (i < n) d0[i] = f2b(s0[i]);
  else if (i < 2 * n) d1[i - n] = f2b(s1[i - n]);
}

// ============================ 64-tile MFMA (proj only) ============================
#define GEMM_PROLOG \
  __shared__ __align__(16) u16 As[64][72]; \
  __shared__ __align__(16) u16 Bs[64][72]; \
  const int t = threadIdx.x; \
  const int lane = t & 63; \
  const int wv_ = t >> 6; \
  const int wr = wv_ >> 1, wc = wv_ & 1; \
  const int l15 = lane & 15, l4 = lane >> 4; \
  const int srow = t >> 2; \
  const int scol = (t & 3) << 4;

#define STAGE_A(AG, ASTRIDE, VALID, ROWIDX, K0) { \
  int4 v0 = {0, 0, 0, 0}, v1 = {0, 0, 0, 0}; \
  if (VALID) { \
    const int4* p_ = (const int4*)&(AG)[(size_t)(ROWIDX) * (ASTRIDE) + (K0) + scol]; \
    v0 = p_[0]; v1 = p_[1]; \
  } \
  *(int4*)&As[srow][scol] = v0; \
  *(int4*)&As[srow][scol + 8] = v1; }

#define STAGE_B(BG, BSTRIDE, ROWIDX, K0) { \
  const int4* p_ = (const int4*)&(BG)[(size_t)(ROWIDX) * (BSTRIDE) + (K0) + scol]; \
  *(int4*)&Bs[srow][scol] = p_[0]; \
  *(int4*)&Bs[srow][scol + 8] = p_[1]; }

#define MFMA_STEP(ACC) { \
  _Pragma("unroll") \
  for (int kc = 0; kc < 2; ++kc) { \
    short8 a0_ = *(const short8*)&As[wr * 32 + 0 + l15][kc * 32 + l4 * 8]; \
    short8 a1_ = *(const short8*)&As[wr * 32 + 16 + l15][kc * 32 + l4 * 8]; \
    short8 b0_ = *(const short8*)&Bs[wc * 32 + 0 + l15][kc * 32 + l4 * 8]; \
    short8 b1_ = *(const short8*)&Bs[wc * 32 + 16 + l15][kc * 32 + l4 * 8]; \
    ACC[0][0] = __builtin_amdgcn_mfma_f32_16x16x32_bf16(a0_, b0_, ACC[0][0], 0, 0, 0); \
    ACC[0][1] = __builtin_amdgcn_mfma_f32_16x16x32_bf16(a0_, b1_, ACC[0][1], 0, 0, 0); \
    ACC[1][0] = __builtin_amdgcn_mfma_f32_16x16x32_bf16(a1_, b0_, ACC[1][0], 0, 0, 0); \
    ACC[1][1] = __builtin_amdgcn_mfma_f32_16x16x32_bf16(a1_, b1_, ACC[1][1], 0, 0, 0); \
  } }

// ============================ 128-tile MFMA (main GEMMs) ============================
#define GEMM128_PROLOG \
  __shared__ __align__(16) u16 As[128][72]; \
  __shared__ __align__(16) u16 Bs[128][72]; \
  const int t = threadIdx.x; \
  const int lane = t & 63; \
  const int wv_ = t >> 6; \
  const int qr = (wv_ >> 1) * 64, qc = (wv_ & 1) * 64; \
  const int l15 = lane & 15, l4 = lane >> 4; \
  const int srow = t >> 1; \
  const int scol = (t & 1) * 32;

#define STAGE128_A(AG, ASTRIDE, VALID, ROWIDX, K0) { \
  int4 v0 = {0,0,0,0}, v1 = {0,0,0,0}, v2 = {0,0,0,0}, v3 = {0,0,0,0}; \
  if (VALID) { \
    const int4* p_ = (const int4*)&(AG)[(size_t)(ROWIDX) * (ASTRIDE) + (K0) + scol]; \
    v0 = p_[0]; v1 = p_[1]; v2 = p_[2]; v3 = p_[3]; \
  } \
  *(int4*)&As[srow][scol] = v0; *(int4*)&As[srow][scol + 8] = v1; \
  *(int4*)&As[srow][scol + 16] = v2; *(int4*)&As[srow][scol + 24] = v3; }

#define STAGE128_B(BG, BSTRIDE, ROWIDX, K0) { \
  const int4* p_ = (const int4*)&(BG)[(size_t)(ROWIDX) * (BSTRIDE) + (K0) + scol]; \
  *(int4*)&Bs[srow][scol] = p_[0]; *(int4*)&Bs[srow][scol + 8] = p_[1]; \
  *(int4*)&Bs[srow][scol + 16] = p_[2]; *(int4*)&Bs[srow][scol + 24] = p_[3]; }

#define MFMA128_STEP(ACC) { \
  _Pragma("unroll") \
  for (int kc = 0; kc < 2; ++kc) { \
    short8 af_[4], bf_[4]; \
    _Pragma("unroll") \
    for (int m = 0; m < 4; ++m) af_[m] = *(const short8*)&As[qr + m * 16 + l15][kc * 32 + l4 * 8]; \
    _Pragma("unroll") \
    for (int n = 0; n < 4; ++n) bf_[n] = *(const short8*)&Bs[qc + n * 16 + l15][kc * 32 + l4 * 8]; \
    _Pragma("unroll") \
    for (int m = 0; m < 4; ++m) \
      _Pragma("unroll") \
      for (int n = 0; n < 4; ++n) \
        ACC[m][n] = __builtin_amdgcn_mfma_f32_16x16x32_bf16(af_[m], bf_[n], ACC[m][n], 0, 0, 0); \
  } }

// ============================ proj (role-bucketed, 64-tile) ============================
__global__ __launch_bounds__(256) void proj_mfma(
    const u16* __restrict__ Xb, const int* __restrict__ perm,
    const int* __restrict__ blkrole,
    const u16* __restrict__ Wqt, const u16* __restrict__ Wet, const u16* __restrict__ Wct,
    const float* __restrict__ bq, const float* __restrict__ be, const float* __restrict__ bc,
    u16* __restrict__ h, u16* __restrict__ pm) {
  const int brole = blkrole[blockIdx.y];
  if (brole < 0) return;
  GEMM_PROLOG
  const int m0 = blockIdx.y * 64;
  const int n0 = blockIdx.x * 64;
  const u16* Bt = (brole == 0) ? Wqt : (brole == 1) ? Wet : Wct;
  const float* bb = (brole == 0) ? bq : (brole == 1) ? be : bc;
  const int prow = perm[m0 + srow];
  floatx4 acc[2][2] = {};
  for (int k0 = 0; k0 < KPAD; k0 += 64) {
    STAGE_A(Xb, KPAD, prow >= 0, prow, k0)
    STAGE_B(Bt, KPAD, n0 + srow, k0)
    __syncthreads();
    MFMA_STEP(acc)
    __syncthreads();
  }
  #pragma unroll
  for (int m = 0; m < 2; ++m)
    #pragma unroll
    for (int reg = 0; reg < 4; ++reg) {
      int gr = m0 + wr * 32 + m * 16 + l4 * 4 + reg;
      int pr = perm[gr];
      if (pr >= 0) {
        #pragma unroll
        for (int n = 0; n < 2; ++n) {
          int c = n0 + wc * 32 + n * 16 + l15;
          float vo = fmaxf(acc[m][n][reg] + bb[c], 0.f);
          u16 ub = f2b(vo);
          h[(size_t)pr * 256 + c] = ub;
          pm[(size_t)pr * 256 + c] = ub;
        }
      }
    }
}

// ============================ V = h @ Wall + ball (128-tile) ============================
__global__ __launch_bounds__(256) void vgemm_mfma(
    const u16* __restrict__ A, const u16* __restrict__ Bt,
    const float* __restrict__ bias, u16* __restrict__ C) {
  GEMM128_PROLOG
  const int m0 = blockIdx.y * 128;
  const int n0 = blockIdx.x * 128;
  const int ar = m0 + srow;
  floatx4 acc[4][4] = {};
  for (int k0 = 0; k0 < 256; k0 += 64) {
    STAGE128_A(A, 256, ar < NN, ar, k0)
    STAGE128_B(Bt, 256, n0 + srow, k0)
    __syncthreads();
    MFMA128_STEP(acc)
    __syncthreads();
  }
  #pragma unroll
  for (int m = 0; m < 4; ++m)
    #pragma unroll
    for (int reg = 0; reg < 4; ++reg) {
      int gr = m0 + qr + m * 16 + l4 * 4 + reg;
      if (gr < NN) {
        #pragma unroll
        for (int n = 0; n < 4; ++n) {
          int c = n0 + qc + n * 16 + l15;
          C[(size_t)gr * 256 + c] = f2b(acc[m][n][reg] + bias[c]);
        }
      }
    }
}

// ============================ aggregation (4-deep ILP gather) ============================
__global__ __launch_bounds__(256) void agg_kernel(
    const int2* __restrict__ srcw, const int* __restrict__ rs,
    const u16* __restrict__ V, u16* __restrict__ comb) {
  int n = blockIdx.x * 4 + (threadIdx.x >> 6);
  int l = threadIdx.x & 63;
  if (n >= NN) return;
  int s = rs[n], e = rs[n + 1];
  float a0 = 0.f, a1 = 0.f, a2 = 0.f, a3 = 0.f;
  float c0 = 0.f, c1 = 0.f, c2 = 0.f, c3 = 0.f;
  const size_t loff = (size_t)l * 4;
  for (int base = s; base < e; base += 64) {
    int2 p = {0, 0};
    if (base + l < e) p = srcw[base + l];
    int cnt = min(64, e - base);
    int j = 0;
    for (; j + 4 <= cnt; j += 4) {
      int s0 = __shfl(p.x, j + 0), s1 = __shfl(p.x, j + 1);
      int s2 = __shfl(p.x, j + 2), s3 = __shfl(p.x, j + 3);
      float w0 = __int_as_float(__shfl(p.y, j + 0));
      float w1 = __int_as_float(__shfl(p.y, j + 1));
      float w2 = __int_as_float(__shfl(p.y, j + 2));
      float w3 = __int_as_float(__shfl(p.y, j + 3));
      ushort4 v0 = *(const ushort4*)&V[(size_t)s0 * 256 + loff];
      ushort4 v1 = *(const ushort4*)&V[(size_t)s1 * 256 + loff];
      ushort4 v2 = *(const ushort4*)&V[(size_t)s2 * 256 + loff];
      ushort4 v3 = *(const ushort4*)&V[(size_t)s3 * 256 + loff];
      a0 = fmaf(w0, b2f(v0.x), a0); a1 = fmaf(w0, b2f(v0.y), a1);
      a2 = fmaf(w0, b2f(v0.z), a2); a3 = fmaf(w0, b2f(v0.w), a3);
      c0 = fmaf(w1, b2f(v1.x), c0); c1 = fmaf(w1, b2f(v1.y), c1);
      c2 = fmaf(w1, b2f(v1.z), c2); c3 = fmaf(w1, b2f(v1.w), c3);
      a0 = fmaf(w2, b2f(v2.x), a0); a1 = fmaf(w2, b2f(v2.y), a1);
      a2 = fmaf(w2, b2f(v2.z), a2); a3 = fmaf(w2, b2f(v2.w), a3);
      c0 = fmaf(w3, b2f(v3.x), c0); c1 = fmaf(w3, b2f(v3.y), c1);
      c2 = fmaf(w3, b2f(v3.z), c2); c3 = fmaf(w3, b2f(v3.w), c3);
    }
    for (; j < cnt; ++j) {
      int src = __shfl(p.x, j);
      float w = __int_as_float(__shfl(p.y, j));
      ushort4 v = *(const ushort4*)&V[(size_t)src * 256 + loff];
      a0 = fmaf(w, b2f(v.x), a0); a1 = fmaf(w, b2f(v.y), a1);
      a2 = fmaf(w, b2f(v.z), a2); a3 = fmaf(w, b2f(v.w), a3);
    }
  }
  a0 += c0; a1 += c1; a2 += c2; a3 += c3;
  ushort4 o;
  o.x = f2b(a0); o.y = f2b(a1); o.z = f2b(a2); o.w = f2b(a3);
  *(ushort4*)&comb[(size_t)n * 256 + loff] = o;
}

// ============================ GRU r,z gates (128-tile) ============================
__global__ __launch_bounds__(256) void grurz_mfma(
    const u16* __restrict__ comb, const u16* __restrict__ pmc,
    const u16* __restrict__ Wiht, const u16* __restrict__ Whht,
    const float* __restrict__ bih, const float* __restrict__ bhh,
    u16* __restrict__ R, u16* __restrict__ Z) {
  GEMM128_PROLOG
  const int m0 = blockIdx.y * 128;
  const int j0 = blockIdx.x * 128;  // 0..384
  const int ar = m0 + srow;
  floatx4 acc[4][4] = {};
  #pragma unroll
  for (int p = 0; p < 2; ++p) {
    const u16* Ag = p ? pmc : comb;
    const u16* Bt = p ? Whht : Wiht;
    for (int k0 = 0; k0 < 256; k0 += 64) {
      STAGE128_A(Ag, 256, ar < NN, ar, k0)
      STAGE128_B(Bt, 256, j0 + srow, k0)
      __syncthreads();
      MFMA128_STEP(acc)
      __syncthreads();
    }
  }
  #pragma unroll
  for (int m = 0; m < 4; ++m)
    #pragma unroll
    for (int reg = 0; reg < 4; ++reg) {
      int gr = m0 + qr + m * 16 + l4 * 4 + reg;
      if (gr < NN) {
        #pragma unroll
        for (int n = 0; n < 4; ++n) {
          int j = j0 + qc + n * 16 + l15;
          float g = sigf(acc[m][n][reg] + bih[j] + bhh[j]);
          if (j < 256) R[(size_t)gr * 256 + j] = f2b(g);
          else         Z[(size_t)gr * 256 + (j - 256)] = f2b(g);
        }
      }
    }
}

// ============================ GRU n-gate + state update (128-tile) ============================
__global__ __launch_bounds__(256) void grun_mfma(
    const u16* __restrict__ comb, const u16* __restrict__ pmc,
    const u16* __restrict__ Wiht, const u16* __restrict__ Whht,
    const float* __restrict__ bih, const float* __restrict__ bhh,
    const u16* __restrict__ R, const u16* __restrict__ Z,
    u16* __restrict__ pmn) {
  GEMM128_PROLOG
  const int m0 = blockIdx.y * 128;
  const int n0 = blockIdx.x * 128;
  const int ar = m0 + srow;
  floatx4 ai[4][4] = {};
  floatx4 ah[4][4] = {};
  for (int k0 = 0; k0 < 256; k0 += 64) {
    STAGE128_A(comb, 256, ar < NN, ar, k0)
    STAGE128_B(Wiht, 256, 512 + n0 + srow, k0)
    __syncthreads();
    MFMA128_STEP(ai)
    __syncthreads();
  }
  for (int k0 = 0; k0 < 256; k0 += 64) {
    STAGE128_A(pmc, 256, ar < NN, ar, k0)
    STAGE128_B(Whht, 256, 512 + n0 + srow, k0)
    __syncthreads();
    MFMA128_STEP(ah)
    __syncthreads();
  }
  #pragma unroll
  for (int m = 0; m < 4; ++m)
    #pragma unroll
    for (int reg = 0; reg < 4; ++reg) {
      int gr = m0 + qr + m * 16 + l4 * 4 + reg;
      if (gr < NN) {
        #pragma unroll
        for (int n = 0; n < 4; ++n) {
          int c = n0 + qc + n * 16 + l15;
          float i_n = ai[m][n][reg] + bih[512 + c];
          float h_n = ah[m][n][reg] + bhh[512 + c];
          float rg = b2f(R[(size_t)gr * 256 + c]);
          float z = b2f(Z[(size_t)gr * 256 + c]);
          float po = b2f(pmc[(size_t)gr * 256 + c]);
          float nn2 = tanhf(i_n + rg * h_n);
          pmn[(size_t)gr * 256 + c] = f2b((1.f - z) * nn2 + z * po);
        }
      }
    }
}

// ============================ tmp = comb @ Wo + bo + h (128-tile) ============================
__global__ __launch_bounds__(256) void wo_mfma(
    const u16* __restrict__ comb, const u16* __restrict__ Wot,
    const float* __restrict__ bo, const u16* __restrict__ h,
    u16* __restrict__ tmp) {
  GEMM128_PROLOG
  const int m0 = blockIdx.y * 128;
  const int n0 = blockIdx.x * 128;
  const int ar = m0 + srow;
  floatx4 acc[4][4] = {};
  for (int k0 = 0; k0 < 256; k0 += 64) {
    STAGE128_A(comb, 256, ar < NN, ar, k0)
    STAGE128_B(Wot, 256, n0 + srow, k0)
    __syncthreads();
    MFMA128_STEP(acc)
    __syncthreads();
  }
  #pragma unroll
  for (int m = 0; m < 4; ++m)
    #pragma unroll
    for (int reg = 0; reg < 4; ++reg) {
      int gr = m0 + qr + m * 16 + l4 * 4 + reg;
      if (gr < NN) {
        #pragma unroll
        for (int n = 0; n < 4; ++n) {
          int c = n0 + qc + n * 16 + l15;
          float v = acc[m][n][reg] + bo[c] + b2f(h[(size_t)gr * 256 + c]);
          tmp[(size_t)gr * 256 + c] = f2b(v);
        }
      }
    }
}

// ============================ LayerNorm (row-wise) ============================
__global__ __launch_bounds__(256) void ln_kernel(
    const u16* __restrict__ tmp, u16* __restrict__ h,
    const float* __restrict__ lnw, const float* __restrict__ lnb) {
  int n = blockIdx.x * 4 + (threadIdx.x >> 6);
  int l = threadIdx.x & 63;
  if (n >= NN) return;
  ushort4 v = *(const ushort4*)&tmp[(size_t)n * 256 + l * 4];
  float x0 = b2f(v.x), x1 = b2f(v.y), x2 = b2f(v.z), x3 = b2f(v.w);
  float s = x0 + x1 + x2 + x3;
  #pragma unroll
  for (int off = 1; off < 64; off <<= 1) s += __shfl_xor(s, off);
  float mu = s * (1.f / 256.f);
  float d0 = x0 - mu, d1 = x1 - mu, d2 = x2 - mu, d3 = x3 - mu;
  float vs = d0 * d0 + d1 * d1 + d2 * d2 + d3 * d3;
  #pragma unroll
  for (int off = 1; off < 64; off <<= 1) vs += __shfl_xor(vs, off);
  float inv = rsqrtf(vs * (1.f / 256.f) + 1e-5f);
  int c = l * 4;
  ushort4 o;
  o.x = f2b(d0 * inv * lnw[c + 0] + lnb[c + 0]);
  o.y = f2b(d1 * inv * lnw[c + 1] + lnb[c + 1]);
  o.z = f2b(d2 * inv * lnw[c + 2] + lnb[c + 2]);
  o.w = f2b(d3 * inv * lnw[c + 3] + lnb[c + 3]);
  *(ushort4*)&h[(size_t)n * 256 + c] = o;
}

// last layer: out = LN(tmp) + pm  (f32, fused epilogue)
__global__ __launch_bounds__(256) void ln_final_kernel(
    const u16* __restrict__ tmp, const u16* __restrict__ pm,
    const float* __restrict__ lnw, const float* __restrict__ lnb,
    float* __restrict__ out) {
  int n = blockIdx.x * 4 + (threadIdx.x >> 6);
  int l = threadIdx.x & 63;
  if (n >= NN) return;
  ushort4 v = *(const ushort4*)&tmp[(size_t)n * 256 + l * 4];
  float x0 = b2f(v.x), x1 = b2f(v.y), x2 = b2f(v.z), x3 = b2f(v.w);
  float s = x0 + x1 + x2 + x3;
  #pragma unroll
  for (int off = 1; off < 64; off <<= 1) s += __shfl_xor(s, off);
  float mu = s * (1.f / 256.f);
  float d0 = x0 - mu, d1 = x1 - mu, d2 = x2 - mu, d3 = x3 - mu;
  float vs = d0 * d0 + d1 * d1 + d2 * d2 + d3 * d3;
  #pragma unroll
  for (int off = 1; off < 64; off <<= 1) vs += __shfl_xor(vs, off);
  float inv = rsqrtf(vs * (1.f / 256.f) + 1e-5f);
  int c = l * 4;
  ushort4 pv = *(const ushort4*)&pm[(size_t)n * 256 + c];
  // match previous numerics: LN result rounded to bf16, then added to pm in f32
  float4 o;
  o.x = b2f(f2b(d0 * inv * lnw[c + 0] + lnb[c + 0])) + b2f(pv.x);
  o.y = b2f(f2b(d1 * inv * lnw[c + 1] + lnb[c + 1])) + b2f(pv.y);
  o.z = b2f(f2b(d2 * inv * lnw[c + 2] + lnb[c + 2])) + b2f(pv.z);
  o.w = b2f(f2b(d3 * inv * lnw[c + 3] + lnb[c + 3])) + b2f(pv.w);
  *(float4*)&out[(size_t)n * 256 + c] = o;
}

extern "C" void kernel_launch(void* const* d_in, const int* in_sizes, int n_in,
                              void* d_out, int out_size, void* d_ws, size_t ws_size,
                              hipStream_t stream) {
  const float* node_feats = (const float*)d_in[0];
  const int* role = (const int*)d_in[1];
  const int* esrc = (const int*)d_in[2];
  const int* edst = (const int*)d_in[3];
  const float* ew = (const float*)d_in[4];
  const float* Wq = (const float*)d_in[5];
  const float* bq = (const float*)d_in[6];
  const float* We = (const float*)d_in[7];
  const float* be = (const float*)d_in[8];
  const float* Wc = (const float*)d_in[9];
  const float* bc = (const float*)d_in[10];
  const float* Wv = (const float*)d_in[11];
  const float* bv = (const float*)d_in[12];
  const float* Wd = (const float*)d_in[13];
  const float* bd = (const float*)d_in[14];
  const float* Wo = (const float*)d_in[15];
  const float* bo = (const float*)d_in[16];
  const float* Wih = (const float*)d_in[17];
  const float* Whh = (const float*)d_in[18];
  const float* bih = (const float*)d_in[19];
  const float* bhh = (const float*)d_in[20];
  const float* lnw = (const float*)d_in[21];
  const float* lnb = (const float*)d_in[22];
  float* out = (float*)d_out;

  char* ws = (char*)d_ws;
  size_t off = 0;
  auto take = [&](size_t bytes) {
    char* p = ws + off;
    off = (off + bytes + 511) & ~(size_t)511;
    return p;
  };
  const size_t NC2 = (size_t)NN * 256 * 2;
  u16* Xb = (u16*)take((size_t)NN * KPAD * 2);
  u16* h = (u16*)take(NC2);
  u16* pm0 = (u16*)take(NC2);
  u16* pm1 = (u16*)take(NC2);
  u16* V = (u16*)take(NC2);   // aliased as R after agg consumes it
  u16* comb = (u16*)take(NC2);
  u16* Z = (u16*)take(NC2);
  u16* tmp = (u16*)take(NC2);
  u16* Wqt = (u16*)take((size_t)256 * KPAD * 2);
  u16* Wet = (u16*)take((size_t)256 * KPAD * 2);
  u16* Wct = (u16*)take((size_t)256 * KPAD * 2);
  u16* Wallt = (u16*)take((size_t)256 * 256 * 2);
  u16* Wot = (u16*)take((size_t)256 * 256 * 2);
  u16* Wiht = (u16*)take((size_t)768 * 256 * 2);
  u16* Whht = (u16*)take((size_t)768 * 256 * 2);
  float* ball = (float*)take(256 * 4);
  int* cnt = (int*)take((size_t)NN * 4);
  int* rs = (int*)take((size_t)(NN + 1) * 4);
  int* ncnt = (int*)take((size_t)NN * 4);
  int2* srcw = (int2*)take((size_t)EE * 8);
  int* cnt3 = (int*)take(16);
  int* pos3 = (int*)take(16);
  int* pbase = (int*)take(16);
  int* blkrole = (int*)take((size_t)NBLK * 4);
  int* perm = (int*)take((size_t)NBLK * 64 * 4);
  int* bsum = (int*)take(64 * 4);
  u16* R = V;

  const int NB_SCAN = (NN + 2047) / 2048;  // 25

  hipMemsetAsync(cnt, 0, (size_t)NN * 4, stream);
  hipMemsetAsync(ncnt, 0, (size_t)NN * 4, stream);
  hipMemsetAsync(cnt3, 0, 16, stream);
  hipMemsetAsync(pos3, 0, 16, stream);
  hipMemsetAsync(perm, 0xFF, (size_t)NBLK * 64 * 4, stream);

  count_kernel<<<(EE + 255) / 256, 256, 0, stream>>>(edst, cnt);
  scan1_kernel<<<NB_SCAN, 256, 0, stream>>>(cnt, rs, bsum);
  scan2_kernel<<<1, 64, 0, stream>>>(bsum, NB_SCAN);
  scan3_kernel<<<(NN + 255) / 256, 256, 0, stream>>>(bsum, rs, NB_SCAN);
  fill_kernel<<<(EE + 255) / 256, 256, 0, stream>>>(edst, rs, ncnt, esrc, ew, srcw);

  role_count<<<(NN + 255) / 256, 256, 0, stream>>>(role, cnt3);
  role_plan<<<1, 256, 0, stream>>>(cnt3, pbase, blkrole);
  role_fill<<<(NN + 255) / 256, 256, 0, stream>>>(role, pbase, pos3, perm);

  xcast_kernel<<<(int)(((size_t)NN * KPAD + 255) / 256), 256, 0, stream>>>(node_feats, Xb);
  wt3_kernel<<<dim3(256, 3), 256, 0, stream>>>(Wq, We, Wc, Wqt, Wet, Wct);
  wallt_kernel<<<256, 256, 0, stream>>>(Wv, Wd, Wallt);
  ball_kernel<<<1, 256, 0, stream>>>(bv, Wd, bd, ball);
  wot_kernel<<<256, 256, 0, stream>>>(Wo, Wot);
  castbf2_kernel<<<(2 * 768 * 256 + 255) / 256, 256, 0, stream>>>(Wih, Whh, Wiht, Whht);

  proj_mfma<<<dim3(4, NBLK), 256, 0, stream>>>(Xb, perm, blkrole, Wqt, Wet, Wct,
                                               bq, be, bc, h, pm0);

  u16* pmc = pm0;
  u16* pmn = pm1;
  const int MB128 = (NN + 127) / 128;  // 391
  for (int layer = 0; layer < NL; ++layer) {
    vgemm_mfma<<<dim3(2, MB128), 256, 0, stream>>>(h, Wallt, ball, V);
    agg_kernel<<<(NN + 3) / 4, 256, 0, stream>>>(srcw, rs, V, comb);
    grurz_mfma<<<dim3(4, MB128), 256, 0, stream>>>(comb, pmc, Wiht, Whht, bih, bhh, R, Z);
    grun_mfma<<<dim3(2, MB128), 256, 0, stream>>>(comb, pmc, Wiht, Whht, bih, bhh, R, Z, pmn);
    wo_mfma<<<dim3(2, MB128), 256, 0, stream>>>(comb, Wot, bo, h, tmp);
    if (layer < NL - 1) {
      ln_kernel<<<(NN + 3) / 4, 256, 0, stream>>>(tmp, h, lnw + layer * 256, lnb + layer * 256);
    } else {
      ln_final_kernel<<<(NN + 3) / 4, 256, 0, stream>>>(tmp, pmn, lnw + layer * 256,
                                                        lnb + layer * 256, out);
    }
    u16* sw = pmc; pmc = pmn; pmn = sw;
  }
}

// Round 6
// 1032.384 us; speedup vs baseline: 3.9697x; 1.1530x over previous
//
#include <hip/hip_runtime.h>
#include <math.h>

#define NN 50000
#define EE 1600000
#define IND 300
#define KPAD 320
#define NL 3
#define NBLK 785
#define AGG_NB 12500

typedef unsigned short u16;
typedef __attribute__((ext_vector_type(8))) short short8;
typedef __attribute__((ext_vector_type(4))) float floatx4;

__device__ __forceinline__ float b2f(u16 u) {
  union { unsigned i; float f; } v; v.i = ((unsigned)u) << 16; return v.f;
}
__device__ __forceinline__ u16 f2b(float f) {
  union { unsigned i; float f; } v; v.f = f;
  unsigned b = v.i; b += 0x7fffu + ((b >> 16) & 1u);
  return (u16)(b >> 16);
}
__device__ __forceinline__ float sigf(float x) { return 1.0f / (1.0f + __expf(-x)); }

// ============================ CSR build ============================
__global__ void count_kernel(const int* __restrict__ dst, int* __restrict__ cnt) {
  int e = blockIdx.x * 256 + threadIdx.x;
  if (e < EE) atomicAdd(&cnt[dst[e]], 1);
}

__global__ __launch_bounds__(256) void scan1_kernel(const int* __restrict__ cnt,
                                                    int* __restrict__ rs,
                                                    int* __restrict__ bsum) {
  __shared__ int ws[4];
  const int t = threadIdx.x, l = t & 63, w = t >> 6;
  const int base = blockIdx.x * 2048 + t * 8;
  int v[8];
  int tot = 0;
  #pragma unroll
  for (int k = 0; k < 8; ++k) {
    int i = base + k;
    v[k] = (i < NN) ? cnt[i] : 0;
    tot += v[k];
  }
  int x = tot;
  #pragma unroll
  for (int off = 1; off < 64; off <<= 1) {
    int y = __shfl_up(x, off);
    if (l >= off) x += y;
  }
  if (l == 63) ws[w] = x;
  __syncthreads();
  int wpre = 0;
  for (int q = 0; q < w; ++q) wpre += ws[q];
  int run = wpre + (x - tot);
  #pragma unroll
  for (int k = 0; k < 8; ++k) {
    int i = base + k;
    if (i < NN) rs[i] = run;
    run += v[k];
  }
  if (t == 255) bsum[blockIdx.x] = wpre + x;
}

__global__ void scan2_kernel(int* __restrict__ bsum, int nb) {
  int l = threadIdx.x;
  int v = (l < nb) ? bsum[l] : 0;
  int x = v;
  #pragma unroll
  for (int off = 1; off < 64; off <<= 1) {
    int y = __shfl_up(x, off);
    if (l >= off) x += y;
  }
  if (l < nb) bsum[l] = x - v;
  if (l == 63) bsum[nb] = x;
}

__global__ void scan3_kernel(const int* __restrict__ bsum, int* __restrict__ rs, int nb) {
  int i = blockIdx.x * 256 + threadIdx.x;
  if (i < NN) rs[i] += bsum[i >> 11];
  if (i == 0) rs[NN] = bsum[nb];
}

__global__ void fill_kernel(const int* __restrict__ dst, const int* __restrict__ rs,
                            int* __restrict__ ncnt, const int* __restrict__ esrc,
                            const float* __restrict__ ew, int2* __restrict__ srcw) {
  int e = blockIdx.x * 256 + threadIdx.x;
  if (e < EE) {
    int d = dst[e];
    int p = atomicAdd(&ncnt[d], 1);
    int2 v;
    v.x = esrc[e];
    v.y = __float_as_int(ew[e]);
    srcw[rs[d] + p] = v;
  }
}

// ============================ role bucketing ============================
__global__ void role_count(const int* __restrict__ role, int* __restrict__ cnt3) {
  __shared__ int lc[3];
  if (threadIdx.x < 3) lc[threadIdx.x] = 0;
  __syncthreads();
  int i = blockIdx.x * 256 + threadIdx.x;
  if (i < NN) atomicAdd(&lc[role[i]], 1);
  __syncthreads();
  if (threadIdx.x < 3) atomicAdd(&cnt3[threadIdx.x], lc[threadIdx.x]);
}

__global__ void role_plan(const int* __restrict__ cnt3, int* __restrict__ pbase,
                          int* __restrict__ blkrole) {
  __shared__ int pb[4];
  if (threadIdx.x == 0) {
    pb[0] = 0;
    for (int b = 0; b < 3; ++b) pb[b + 1] = pb[b] + (((cnt3[b] + 63) >> 6) << 6);
    for (int b = 0; b < 4; ++b) pbase[b] = pb[b];
  }
  __syncthreads();
  for (int blk = threadIdx.x; blk < NBLK; blk += 256) {
    int m0 = blk * 64;
    int r = -1;
    for (int b = 0; b < 3; ++b)
      if (m0 >= pb[b] && m0 < pb[b + 1]) r = b;
    blkrole[blk] = r;
  }
}

__global__ void role_fill(const int* __restrict__ role, const int* __restrict__ pbase,
                          int* __restrict__ pos3, int* __restrict__ perm) {
  __shared__ int lcnt[3], lbase[3];
  int i = blockIdx.x * 256 + threadIdx.x;
  if (threadIdx.x < 3) lcnt[threadIdx.x] = 0;
  __syncthreads();
  int r = 0, lr = 0;
  bool valid = (i < NN);
  if (valid) {
    r = role[i];
    lr = atomicAdd(&lcnt[r], 1);
  }
  __syncthreads();
  if (threadIdx.x < 3) lbase[threadIdx.x] = atomicAdd(&pos3[threadIdx.x], lcnt[threadIdx.x]);
  __syncthreads();
  if (valid) perm[pbase[r] + lbase[r] + lr] = i;
}

// ============================ weight prep ============================
__global__ void xcast_kernel(const float* __restrict__ X, u16* __restrict__ Xb) {
  size_t i = (size_t)blockIdx.x * 256 + threadIdx.x;
  if (i >= (size_t)NN * KPAD) return;
  int r = (int)(i / KPAD), k = (int)(i % KPAD);
  Xb[i] = (k < IND) ? f2b(X[(size_t)r * IND + k]) : (u16)0;
}

__global__ void wt3_kernel(const float* __restrict__ Wq, const float* __restrict__ We,
                           const float* __restrict__ Wc, u16* __restrict__ Wqt,
                           u16* __restrict__ Wet, u16* __restrict__ Wct) {
  int n = blockIdx.x;
  int which = blockIdx.y;
  const float* W = (which == 0) ? Wq : (which == 1) ? We : Wc;
  u16* Wt = (which == 0) ? Wqt : (which == 1) ? Wet : Wct;
  for (int k = threadIdx.x; k < KPAD; k += 256)
    Wt[(size_t)n * KPAD + k] = (k < IND) ? f2b(W[(size_t)k * 256 + n]) : (u16)0;
}

__global__ void wallt_kernel(const float* __restrict__ Wv, const float* __restrict__ Wd,
                             u16* __restrict__ Wallt) {
  int i = blockIdx.x;
  int c = threadIdx.x;
  int hd = c >> 6, j = c & 63;
  const float* wv = &Wv[hd * (256 * 64) + i * 64];
  float s = 0.f;
  #pragma unroll
  for (int m = 0; m < 64; ++m) s = fmaf(wv[m], Wd[m * 64 + j], s);
  Wallt[(size_t)c * 256 + i] = f2b(s);
}

__global__ void ball_kernel(const float* __restrict__ bv, const float* __restrict__ Wd,
                            const float* __restrict__ bd, float* __restrict__ ball) {
  int c = threadIdx.x;
  int hd = c >> 6, j = c & 63;
  float s = bd[j];
  #pragma unroll
  for (int m = 0; m < 64; ++m) s = fmaf(bv[hd * 64 + m], Wd[m * 64 + j], s);
  ball[c] = s;
}

__global__ void wot_kernel(const float* __restrict__ Wo, u16* __restrict__ Wot) {
  int n = blockIdx.x;
  int k = threadIdx.x;
  Wot[(size_t)n * 256 + k] = f2b(Wo[(size_t)k * 256 + n]);
}

__global__ void castbf2_kernel(const float* __restrict__ s0, const float* __restrict__ s1,
                               u16* __restrict__ d0, u16* __restrict__ d1) {
  int i = blockIdx.x * 256 + threadIdx.x;
  const int n = 768 * 256;
  if (i < n) d0[i] = f2b(s0[i]);
  else if (i < 2 * n) d1[i - n] = f2b(s1[i - n]);
}

// ============================ 64-tile MFMA (proj) ============================
#define GEMM_PROLOG \
  __shared__ __align__(16) u16 As[64][72]; \
  __shared__ __align__(16) u16 Bs[64][72]; \
  const int t = threadIdx.x; \
  const int lane = t & 63; \
  const int wv_ = t >> 6; \
  const int wr = wv_ >> 1, wc = wv_ & 1; \
  const int l15 = lane & 15, l4 = lane >> 4; \
  const int srow = t >> 2; \
  const int scol = (t & 3) << 4;

#define STAGE_A(AG, ASTRIDE, VALID, ROWIDX, K0) { \
  int4 v0 = {0, 0, 0, 0}, v1 = {0, 0, 0, 0}; \
  if (VALID) { \
    const int4* p_ = (const int4*)&(AG)[(size_t)(ROWIDX) * (ASTRIDE) + (K0) + scol]; \
    v0 = p_[0]; v1 = p_[1]; \
  } \
  *(int4*)&As[srow][scol] = v0; \
  *(int4*)&As[srow][scol + 8] = v1; }

#define STAGE_B(BG, BSTRIDE, ROWIDX, K0) { \
  const int4* p_ = (const int4*)&(BG)[(size_t)(ROWIDX) * (BSTRIDE) + (K0) + scol]; \
  *(int4*)&Bs[srow][scol] = p_[0]; \
  *(int4*)&Bs[srow][scol + 8] = p_[1]; }

#define MFMA_STEP(ACC) { \
  _Pragma("unroll") \
  for (int kc = 0; kc < 2; ++kc) { \
    short8 a0_ = *(const short8*)&As[wr * 32 + 0 + l15][kc * 32 + l4 * 8]; \
    short8 a1_ = *(const short8*)&As[wr * 32 + 16 + l15][kc * 32 + l4 * 8]; \
    short8 b0_ = *(const short8*)&Bs[wc * 32 + 0 + l15][kc * 32 + l4 * 8]; \
    short8 b1_ = *(const short8*)&Bs[wc * 32 + 16 + l15][kc * 32 + l4 * 8]; \
    ACC[0][0] = __builtin_amdgcn_mfma_f32_16x16x32_bf16(a0_, b0_, ACC[0][0], 0, 0, 0); \
    ACC[0][1] = __builtin_amdgcn_mfma_f32_16x16x32_bf16(a0_, b1_, ACC[0][1], 0, 0, 0); \
    ACC[1][0] = __builtin_amdgcn_mfma_f32_16x16x32_bf16(a1_, b0_, ACC[1][0], 0, 0, 0); \
    ACC[1][1] = __builtin_amdgcn_mfma_f32_16x16x32_bf16(a1_, b1_, ACC[1][1], 0, 0, 0); \
  } }

// ============================ 128-tile MFMA (vgemm / wo) ============================
#define GEMM128_PROLOG \
  __shared__ __align__(16) u16 As[128][72]; \
  __shared__ __align__(16) u16 Bs[128][72]; \
  const int t = threadIdx.x; \
  const int lane = t & 63; \
  const int wv_ = t >> 6; \
  const int qr = (wv_ >> 1) * 64, qc = (wv_ & 1) * 64; \
  const int l15 = lane & 15, l4 = lane >> 4; \
  const int srow = t >> 1; \
  const int scol = (t & 1) * 32;

#define STAGE128_A(AG, ASTRIDE, VALID, ROWIDX, K0) { \
  int4 v0 = {0,0,0,0}, v1 = {0,0,0,0}, v2 = {0,0,0,0}, v3 = {0,0,0,0}; \
  if (VALID) { \
    const int4* p_ = (const int4*)&(AG)[(size_t)(ROWIDX) * (ASTRIDE) + (K0) + scol]; \
    v0 = p_[0]; v1 = p_[1]; v2 = p_[2]; v3 = p_[3]; \
  } \
  *(int4*)&As[srow][scol] = v0; *(int4*)&As[srow][scol + 8] = v1; \
  *(int4*)&As[srow][scol + 16] = v2; *(int4*)&As[srow][scol + 24] = v3; }

#define STAGE128_B(BG, BSTRIDE, ROWIDX, K0) { \
  const int4* p_ = (const int4*)&(BG)[(size_t)(ROWIDX) * (BSTRIDE) + (K0) + scol]; \
  *(int4*)&Bs[srow][scol] = p_[0]; *(int4*)&Bs[srow][scol + 8] = p_[1]; \
  *(int4*)&Bs[srow][scol + 16] = p_[2]; *(int4*)&Bs[srow][scol + 24] = p_[3]; }

#define MFMA128_STEP(ACC) { \
  _Pragma("unroll") \
  for (int kc = 0; kc < 2; ++kc) { \
    short8 af_[4], bf_[4]; \
    _Pragma("unroll") \
    for (int m = 0; m < 4; ++m) af_[m] = *(const short8*)&As[qr + m * 16 + l15][kc * 32 + l4 * 8]; \
    _Pragma("unroll") \
    for (int n = 0; n < 4; ++n) bf_[n] = *(const short8*)&Bs[qc + n * 16 + l15][kc * 32 + l4 * 8]; \
    _Pragma("unroll") \
    for (int m = 0; m < 4; ++m) \
      _Pragma("unroll") \
      for (int n = 0; n < 4; ++n) \
        ACC[m][n] = __builtin_amdgcn_mfma_f32_16x16x32_bf16(af_[m], bf_[n], ACC[m][n], 0, 0, 0); \
  } }

// ============================ proj ============================
__global__ __launch_bounds__(256) void proj_mfma(
    const u16* __restrict__ Xb, const int* __restrict__ perm,
    const int* __restrict__ blkrole,
    const u16* __restrict__ Wqt, const u16* __restrict__ Wet, const u16* __restrict__ Wct,
    const float* __restrict__ bq, const float* __restrict__ be, const float* __restrict__ bc,
    u16* __restrict__ h, u16* __restrict__ pm) {
  const int brole = blkrole[blockIdx.y];
  if (brole < 0) return;
  GEMM_PROLOG
  const int m0 = blockIdx.y * 64;
  const int n0 = blockIdx.x * 64;
  const u16* Bt = (brole == 0) ? Wqt : (brole == 1) ? Wet : Wct;
  const float* bb = (brole == 0) ? bq : (brole == 1) ? be : bc;
  const int prow = perm[m0 + srow];
  floatx4 acc[2][2] = {};
  for (int k0 = 0; k0 < KPAD; k0 += 64) {
    STAGE_A(Xb, KPAD, prow >= 0, prow, k0)
    STAGE_B(Bt, KPAD, n0 + srow, k0)
    __syncthreads();
    MFMA_STEP(acc)
    __syncthreads();
  }
  #pragma unroll
  for (int m = 0; m < 2; ++m)
    #pragma unroll
    for (int reg = 0; reg < 4; ++reg) {
      int gr = m0 + wr * 32 + m * 16 + l4 * 4 + reg;
      int pr = perm[gr];
      if (pr >= 0) {
        #pragma unroll
        for (int n = 0; n < 2; ++n) {
          int c = n0 + wc * 32 + n * 16 + l15;
          float vo = fmaxf(acc[m][n][reg] + bb[c], 0.f);
          u16 ub = f2b(vo);
          h[(size_t)pr * 256 + c] = ub;
          pm[(size_t)pr * 256 + c] = ub;
        }
      }
    }
}

// ============================ V = h @ Wall + ball ============================
__global__ __launch_bounds__(256) void vgemm_mfma(
    const u16* __restrict__ A, const u16* __restrict__ Bt,
    const float* __restrict__ bias, u16* __restrict__ C) {
  GEMM128_PROLOG
  const int m0 = blockIdx.y * 128;
  const int n0 = blockIdx.x * 128;
  const int ar = m0 + srow;
  floatx4 acc[4][4] = {};
  for (int k0 = 0; k0 < 256; k0 += 64) {
    STAGE128_A(A, 256, ar < NN, ar, k0)
    STAGE128_B(Bt, 256, n0 + srow, k0)
    __syncthreads();
    MFMA128_STEP(acc)
    __syncthreads();
  }
  #pragma unroll
  for (int m = 0; m < 4; ++m)
    #pragma unroll
    for (int reg = 0; reg < 4; ++reg) {
      int gr = m0 + qr + m * 16 + l4 * 4 + reg;
      if (gr < NN) {
        #pragma unroll
        for (int n = 0; n < 4; ++n) {
          int c = n0 + qc + n * 16 + l15;
          C[(size_t)gr * 256 + c] = f2b(acc[m][n][reg] + bias[c]);
        }
      }
    }
}

// ============================ aggregation (column-sliced x2, ILP-4) ============================
__global__ __launch_bounds__(256) void agg_kernel(
    const int2* __restrict__ srcw, const int* __restrict__ rs,
    const u16* __restrict__ V, u16* __restrict__ comb) {
  int bid = blockIdx.x;
  int slice = (bid >= AGG_NB) ? 1 : 0;
  int nb = bid - slice * AGG_NB;
  int n = nb * 4 + (threadIdx.x >> 6);
  int l = threadIdx.x & 63;
  if (n >= NN) return;
  int s = rs[n], e = rs[n + 1];
  const size_t coff = (size_t)(slice << 7) + l * 2;
  float a0 = 0.f, a1 = 0.f, c0 = 0.f, c1 = 0.f;
  for (int base = s; base < e; base += 64) {
    int2 p = {0, 0};
    if (base + l < e) p = srcw[base + l];
    int cnt = min(64, e - base);
    int j = 0;
    for (; j + 4 <= cnt; j += 4) {
      int s0 = __shfl(p.x, j + 0), s1 = __shfl(p.x, j + 1);
      int s2 = __shfl(p.x, j + 2), s3 = __shfl(p.x, j + 3);
      float w0 = __int_as_float(__shfl(p.y, j + 0));
      float w1 = __int_as_float(__shfl(p.y, j + 1));
      float w2 = __int_as_float(__shfl(p.y, j + 2));
      float w3 = __int_as_float(__shfl(p.y, j + 3));
      ushort2 v0 = *(const ushort2*)&V[(size_t)s0 * 256 + coff];
      ushort2 v1 = *(const ushort2*)&V[(size_t)s1 * 256 + coff];
      ushort2 v2 = *(const ushort2*)&V[(size_t)s2 * 256 + coff];
      ushort2 v3 = *(const ushort2*)&V[(size_t)s3 * 256 + coff];
      a0 = fmaf(w0, b2f(v0.x), a0); a1 = fmaf(w0, b2f(v0.y), a1);
      c0 = fmaf(w1, b2f(v1.x), c0); c1 = fmaf(w1, b2f(v1.y), c1);
      a0 = fmaf(w2, b2f(v2.x), a0); a1 = fmaf(w2, b2f(v2.y), a1);
      c0 = fmaf(w3, b2f(v3.x), c0); c1 = fmaf(w3, b2f(v3.y), c1);
    }
    for (; j < cnt; ++j) {
      int src = __shfl(p.x, j);
      float w = __int_as_float(__shfl(p.y, j));
      ushort2 v = *(const ushort2*)&V[(size_t)src * 256 + coff];
      a0 = fmaf(w, b2f(v.x), a0); a1 = fmaf(w, b2f(v.y), a1);
    }
  }
  a0 += c0; a1 += c1;
  ushort2 o;
  o.x = f2b(a0); o.y = f2b(a1);
  *(ushort2*)&comb[(size_t)n * 256 + coff] = o;
}

// ============================ fused GRU (all gates + state update) ============================
// block: 64 rows x 64 gate-cols; 6 accumulator sets: {r,z,n} x {comb@Wih, pm@Whh}
__global__ __launch_bounds__(256) void gru_mfma(
    const u16* __restrict__ comb, const u16* __restrict__ pmc,
    const u16* __restrict__ Wiht, const u16* __restrict__ Whht,
    const float* __restrict__ bih, const float* __restrict__ bhh,
    u16* __restrict__ pmn) {
  __shared__ __align__(16) u16 As[2][64][72];
  __shared__ __align__(16) u16 Bs[6][64][72];
  const int t = threadIdx.x;
  const int lane = t & 63;
  const int wv_ = t >> 6;
  const int wr = wv_ >> 1, wc = wv_ & 1;
  const int l15 = lane & 15, l4 = lane >> 4;
  const int srow = t >> 2;
  const int scol = (t & 3) << 4;
  const int m0 = blockIdx.y * 64;
  const int cb = blockIdx.x;      // 0..3 -> 64-col slice of hidden
  const int ar = m0 + srow;
  const bool av = ar < NN;
  floatx4 acc[6][2][2] = {};
  for (int k0 = 0; k0 < 256; k0 += 64) {
    {
      int4 v0 = {0,0,0,0}, v1 = {0,0,0,0}, u0 = {0,0,0,0}, u1 = {0,0,0,0};
      if (av) {
        const int4* pa = (const int4*)&comb[(size_t)ar * 256 + k0 + scol];
        v0 = pa[0]; v1 = pa[1];
        const int4* pb = (const int4*)&pmc[(size_t)ar * 256 + k0 + scol];
        u0 = pb[0]; u1 = pb[1];
      }
      *(int4*)&As[0][srow][scol] = v0; *(int4*)&As[0][srow][scol + 8] = v1;
      *(int4*)&As[1][srow][scol] = u0; *(int4*)&As[1][srow][scol + 8] = u1;
    }
    #pragma unroll
    for (int g = 0; g < 3; ++g) {
      size_t row = (size_t)(g * 256 + cb * 64 + srow);
      const int4* p1 = (const int4*)&Wiht[row * 256 + k0 + scol];
      *(int4*)&Bs[g][srow][scol] = p1[0];
      *(int4*)&Bs[g][srow][scol + 8] = p1[1];
      const int4* p2 = (const int4*)&Whht[row * 256 + k0 + scol];
      *(int4*)&Bs[3 + g][srow][scol] = p2[0];
      *(int4*)&Bs[3 + g][srow][scol + 8] = p2[1];
    }
    __syncthreads();
    #pragma unroll
    for (int kc = 0; kc < 2; ++kc) {
      short8 a0f[2], a1f[2];
      #pragma unroll
      for (int m = 0; m < 2; ++m) {
        a0f[m] = *(const short8*)&As[0][wr * 32 + m * 16 + l15][kc * 32 + l4 * 8];
        a1f[m] = *(const short8*)&As[1][wr * 32 + m * 16 + l15][kc * 32 + l4 * 8];
      }
      #pragma unroll
      for (int g = 0; g < 3; ++g) {
        short8 b0 = *(const short8*)&Bs[g][wc * 32 + 0 + l15][kc * 32 + l4 * 8];
        short8 b1 = *(const short8*)&Bs[g][wc * 32 + 16 + l15][kc * 32 + l4 * 8];
        acc[g][0][0] = __builtin_amdgcn_mfma_f32_16x16x32_bf16(a0f[0], b0, acc[g][0][0], 0, 0, 0);
        acc[g][0][1] = __builtin_amdgcn_mfma_f32_16x16x32_bf16(a0f[0], b1, acc[g][0][1], 0, 0, 0);
        acc[g][1][0] = __builtin_amdgcn_mfma_f32_16x16x32_bf16(a0f[1], b0, acc[g][1][0], 0, 0, 0);
        acc[g][1][1] = __builtin_amdgcn_mfma_f32_16x16x32_bf16(a0f[1], b1, acc[g][1][1], 0, 0, 0);
      }
      #pragma unroll
      for (int g = 3; g < 6; ++g) {
        short8 b0 = *(const short8*)&Bs[g][wc * 32 + 0 + l15][kc * 32 + l4 * 8];
        short8 b1 = *(const short8*)&Bs[g][wc * 32 + 16 + l15][kc * 32 + l4 * 8];
        acc[g][0][0] = __builtin_amdgcn_mfma_f32_16x16x32_bf16(a1f[0], b0, acc[g][0][0], 0, 0, 0);
        acc[g][0][1] = __builtin_amdgcn_mfma_f32_16x16x32_bf16(a1f[0], b1, acc[g][0][1], 0, 0, 0);
        acc[g][1][0] = __builtin_amdgcn_mfma_f32_16x16x32_bf16(a1f[1], b0, acc[g][1][0], 0, 0, 0);
        acc[g][1][1] = __builtin_amdgcn_mfma_f32_16x16x32_bf16(a1f[1], b1, acc[g][1][1], 0, 0, 0);
      }
    }
    __syncthreads();
  }
  #pragma unroll
  for (int m = 0; m < 2; ++m)
    #pragma unroll
    for (int reg = 0; reg < 4; ++reg) {
      int gr = m0 + wr * 32 + m * 16 + l4 * 4 + reg;
      if (gr < NN) {
        #pragma unroll
        for (int n = 0; n < 2; ++n) {
          int c = cb * 64 + wc * 32 + n * 16 + l15;
          float r = sigf(acc[0][m][n][reg] + acc[3][m][n][reg] + bih[c] + bhh[c]);
          float z = sigf(acc[1][m][n][reg] + acc[4][m][n][reg] + bih[256 + c] + bhh[256 + c]);
          float i_n = acc[2][m][n][reg] + bih[512 + c];
          float h_n = acc[5][m][n][reg] + bhh[512 + c];
          float nn2 = tanhf(i_n + r * h_n);
          float po = b2f(pmc[(size_t)gr * 256 + c]);
          pmn[(size_t)gr * 256 + c] = f2b((1.f - z) * nn2 + z * po);
        }
      }
    }
}

// ============================ tmp = comb @ Wo + bo + h ============================
__global__ __launch_bounds__(256) void wo_mfma(
    const u16* __restrict__ comb, const u16* __restrict__ Wot,
    const float* __restrict__ bo, const u16* __restrict__ h,
    u16* __restrict__ tmp) {
  GEMM128_PROLOG
  const int m0 = blockIdx.y * 128;
  const int n0 = blockIdx.x * 128;
  const int ar = m0 + srow;
  floatx4 acc[4][4] = {};
  for (int k0 = 0; k0 < 256; k0 += 64) {
    STAGE128_A(comb, 256, ar < NN, ar, k0)
    STAGE128_B(Wot, 256, n0 + srow, k0)
    __syncthreads();
    MFMA128_STEP(acc)
    __syncthreads();
  }
  #pragma unroll
  for (int m = 0; m < 4; ++m)
    #pragma unroll
    for (int reg = 0; reg < 4; ++reg) {
      int gr = m0 + qr + m * 16 + l4 * 4 + reg;
      if (gr < NN) {
        #pragma unroll
        for (int n = 0; n < 4; ++n) {
          int c = n0 + qc + n * 16 + l15;
          float v = acc[m][n][reg] + bo[c] + b2f(h[(size_t)gr * 256 + c]);
          tmp[(size_t)gr * 256 + c] = f2b(v);
        }
      }
    }
}

// ============================ LayerNorm ============================
__global__ __launch_bounds__(256) void ln_kernel(
    const u16* __restrict__ tmp, u16* __restrict__ h,
    const float* __restrict__ lnw, const float* __restrict__ lnb) {
  int n = blockIdx.x * 4 + (threadIdx.x >> 6);
  int l = threadIdx.x & 63;
  if (n >= NN) return;
  ushort4 v = *(const ushort4*)&tmp[(size_t)n * 256 + l * 4];
  float x0 = b2f(v.x), x1 = b2f(v.y), x2 = b2f(v.z), x3 = b2f(v.w);
  float s = x0 + x1 + x2 + x3;
  #pragma unroll
  for (int off = 1; off < 64; off <<= 1) s += __shfl_xor(s, off);
  float mu = s * (1.f / 256.f);
  float d0 = x0 - mu, d1 = x1 - mu, d2 = x2 - mu, d3 = x3 - mu;
  float vs = d0 * d0 + d1 * d1 + d2 * d2 + d3 * d3;
  #pragma unroll
  for (int off = 1; off < 64; off <<= 1) vs += __shfl_xor(vs, off);
  float inv = rsqrtf(vs * (1.f / 256.f) + 1e-5f);
  int c = l * 4;
  ushort4 o;
  o.x = f2b(d0 * inv * lnw[c + 0] + lnb[c + 0]);
  o.y = f2b(d1 * inv * lnw[c + 1] + lnb[c + 1]);
  o.z = f2b(d2 * inv * lnw[c + 2] + lnb[c + 2]);
  o.w = f2b(d3 * inv * lnw[c + 3] + lnb[c + 3]);
  *(ushort4*)&h[(size_t)n * 256 + c] = o;
}

__global__ __launch_bounds__(256) void ln_final_kernel(
    const u16* __restrict__ tmp, const u16* __restrict__ pm,
    const float* __restrict__ lnw, const float* __restrict__ lnb,
    float* __restrict__ out) {
  int n = blockIdx.x * 4 + (threadIdx.x >> 6);
  int l = threadIdx.x & 63;
  if (n >= NN) return;
  ushort4 v = *(const ushort4*)&tmp[(size_t)n * 256 + l * 4];
  float x0 = b2f(v.x), x1 = b2f(v.y), x2 = b2f(v.z), x3 = b2f(v.w);
  float s = x0 + x1 + x2 + x3;
  #pragma unroll
  for (int off = 1; off < 64; off <<= 1) s += __shfl_xor(s, off);
  float mu = s * (1.f / 256.f);
  float d0 = x0 - mu, d1 = x1 - mu, d2 = x2 - mu, d3 = x3 - mu;
  float vs = d0 * d0 + d1 * d1 + d2 * d2 + d3 * d3;
  #pragma unroll
  for (int off = 1; off < 64; off <<= 1) vs += __shfl_xor(vs, off);
  float inv = rsqrtf(vs * (1.f / 256.f) + 1e-5f);
  int c = l * 4;
  ushort4 pv = *(const ushort4*)&pm[(size_t)n * 256 + c];
  float4 o;
  o.x = b2f(f2b(d0 * inv * lnw[c + 0] + lnb[c + 0])) + b2f(pv.x);
  o.y = b2f(f2b(d1 * inv * lnw[c + 1] + lnb[c + 1])) + b2f(pv.y);
  o.z = b2f(f2b(d2 * inv * lnw[c + 2] + lnb[c + 2])) + b2f(pv.z);
  o.w = b2f(f2b(d3 * inv * lnw[c + 3] + lnb[c + 3])) + b2f(pv.w);
  *(float4*)&out[(size_t)n * 256 + c] = o;
}

extern "C" void kernel_launch(void* const* d_in, const int* in_sizes, int n_in,
                              void* d_out, int out_size, void* d_ws, size_t ws_size,
                              hipStream_t stream) {
  const float* node_feats = (const float*)d_in[0];
  const int* role = (const int*)d_in[1];
  const int* esrc = (const int*)d_in[2];
  const int* edst = (const int*)d_in[3];
  const float* ew = (const float*)d_in[4];
  const float* Wq = (const float*)d_in[5];
  const float* bq = (const float*)d_in[6];
  const float* We = (const float*)d_in[7];
  const float* be = (const float*)d_in[8];
  const float* Wc = (const float*)d_in[9];
  const float* bc = (const float*)d_in[10];
  const float* Wv = (const float*)d_in[11];
  const float* bv = (const float*)d_in[12];
  const float* Wd = (const float*)d_in[13];
  const float* bd = (const float*)d_in[14];
  const float* Wo = (const float*)d_in[15];
  const float* bo = (const float*)d_in[16];
  const float* Wih = (const float*)d_in[17];
  const float* Whh = (const float*)d_in[18];
  const float* bih = (const float*)d_in[19];
  const float* bhh = (const float*)d_in[20];
  const float* lnw = (const float*)d_in[21];
  const float* lnb = (const float*)d_in[22];
  float* out = (float*)d_out;

  char* ws = (char*)d_ws;
  size_t off = 0;
  auto take = [&](size_t bytes) {
    char* p = ws + off;
    off = (off + bytes + 511) & ~(size_t)511;
    return p;
  };
  const size_t NC2 = (size_t)NN * 256 * 2;
  u16* Xb = (u16*)take((size_t)NN * KPAD * 2);
  u16* h = (u16*)take(NC2);
  u16* pm0 = (u16*)take(NC2);
  u16* pm1 = (u16*)take(NC2);
  u16* V = (u16*)take(NC2);
  u16* comb = (u16*)take(NC2);
  u16* tmp = (u16*)take(NC2);
  u16* Wqt = (u16*)take((size_t)256 * KPAD * 2);
  u16* Wet = (u16*)take((size_t)256 * KPAD * 2);
  u16* Wct = (u16*)take((size_t)256 * KPAD * 2);
  u16* Wallt = (u16*)take((size_t)256 * 256 * 2);
  u16* Wot = (u16*)take((size_t)256 * 256 * 2);
  u16* Wiht = (u16*)take((size_t)768 * 256 * 2);
  u16* Whht = (u16*)take((size_t)768 * 256 * 2);
  float* ball = (float*)take(256 * 4);
  int* cnt = (int*)take((size_t)NN * 4);
  int* rs = (int*)take((size_t)(NN + 1) * 4);
  int* ncnt = (int*)take((size_t)NN * 4);
  int2* srcw = (int2*)take((size_t)EE * 8);
  int* cnt3 = (int*)take(16);
  int* pos3 = (int*)take(16);
  int* pbase = (int*)take(16);
  int* blkrole = (int*)take((size_t)NBLK * 4);
  int* perm = (int*)take((size_t)NBLK * 64 * 4);
  int* bsum = (int*)take(64 * 4);

  const int NB_SCAN = (NN + 2047) / 2048;  // 25

  hipMemsetAsync(cnt, 0, (size_t)NN * 4, stream);
  hipMemsetAsync(ncnt, 0, (size_t)NN * 4, stream);
  hipMemsetAsync(cnt3, 0, 16, stream);
  hipMemsetAsync(pos3, 0, 16, stream);
  hipMemsetAsync(perm, 0xFF, (size_t)NBLK * 64 * 4, stream);

  count_kernel<<<(EE + 255) / 256, 256, 0, stream>>>(edst, cnt);
  scan1_kernel<<<NB_SCAN, 256, 0, stream>>>(cnt, rs, bsum);
  scan2_kernel<<<1, 64, 0, stream>>>(bsum, NB_SCAN);
  scan3_kernel<<<(NN + 255) / 256, 256, 0, stream>>>(bsum, rs, NB_SCAN);
  fill_kernel<<<(EE + 255) / 256, 256, 0, stream>>>(edst, rs, ncnt, esrc, ew, srcw);

  role_count<<<(NN + 255) / 256, 256, 0, stream>>>(role, cnt3);
  role_plan<<<1, 256, 0, stream>>>(cnt3, pbase, blkrole);
  role_fill<<<(NN + 255) / 256, 256, 0, stream>>>(role, pbase, pos3, perm);

  xcast_kernel<<<(int)(((size_t)NN * KPAD + 255) / 256), 256, 0, stream>>>(node_feats, Xb);
  wt3_kernel<<<dim3(256, 3), 256, 0, stream>>>(Wq, We, Wc, Wqt, Wet, Wct);
  wallt_kernel<<<256, 256, 0, stream>>>(Wv, Wd, Wallt);
  ball_kernel<<<1, 256, 0, stream>>>(bv, Wd, bd, ball);
  wot_kernel<<<256, 256, 0, stream>>>(Wo, Wot);
  castbf2_kernel<<<(2 * 768 * 256 + 255) / 256, 256, 0, stream>>>(Wih, Whh, Wiht, Whht);

  proj_mfma<<<dim3(4, NBLK), 256, 0, stream>>>(Xb, perm, blkrole, Wqt, Wet, Wct,
                                               bq, be, bc, h, pm0);

  u16* pmc = pm0;
  u16* pmn = pm1;
  const int MB128 = (NN + 127) / 128;  // 391
  const int MB64 = (NN + 63) / 64;     // 782
  for (int layer = 0; layer < NL; ++layer) {
    vgemm_mfma<<<dim3(2, MB128), 256, 0, stream>>>(h, Wallt, ball, V);
    agg_kernel<<<2 * AGG_NB, 256, 0, stream>>>(srcw, rs, V, comb);
    gru_mfma<<<dim3(4, MB64), 256, 0, stream>>>(comb, pmc, Wiht, Whht, bih, bhh, pmn);
    wo_mfma<<<dim3(2, MB128), 256, 0, stream>>>(comb, Wot, bo, h, tmp);
    if (layer < NL - 1) {
      ln_kernel<<<(NN + 3) / 4, 256, 0, stream>>>(tmp, h, lnw + layer * 256, lnb + layer * 256);
    } else {
      ln_final_kernel<<<(NN + 3) / 4, 256, 0, stream>>>(tmp, pmn, lnw + layer * 256,
                                                        lnb + layer * 256, out);
    }
    u16* sw = pmc; pmc = pmn; pmn = sw;
  }
}